// Round 1
// baseline (598.908 us; speedup 1.0000x reference)
//
#include <hip/hip_runtime.h>
#include <cstddef>

// Problem constants (match reference)
constexpr int cN0 = 100000;
constexpr int cN1 = 50000;
constexpr int cN2 = 25000;
constexpr int cE0 = 400000;
constexpr int cE1 = 200000;
constexpr float SLOPE = 0.2f;

// ---------------- CSR build ----------------

__global__ void hist_kernel(const int* __restrict__ dst, int E, int* __restrict__ cnt) {
    int i = blockIdx.x * blockDim.x + threadIdx.x;
    if (i < E) atomicAdd(&cnt[dst[i]], 1);
}

// single-block exclusive scan; writes offs[0..n] and cursor[0..n-1]
__global__ __launch_bounds__(1024) void scan_kernel(const int* __restrict__ cnt, int n,
                                                    int* __restrict__ offs, int* __restrict__ cursor) {
    __shared__ int wsum[16];
    __shared__ int carry_s;
    int lane = threadIdx.x & 63, wid = threadIdx.x >> 6;
    if (threadIdx.x == 0) carry_s = 0;
    __syncthreads();
    for (int base = 0; base < n; base += 1024) {
        int i = base + (int)threadIdx.x;
        int v = (i < n) ? cnt[i] : 0;
        int x = v;
        #pragma unroll
        for (int o = 1; o < 64; o <<= 1) {
            int t = __shfl_up(x, o);
            if (lane >= o) x += t;
        }
        if (lane == 63) wsum[wid] = x;
        __syncthreads();
        int woff = 0;
        for (int w = 0; w < wid; ++w) woff += wsum[w];
        int carry = carry_s;
        int excl = carry + woff + x - v;
        if (i < n) { offs[i] = excl; cursor[i] = excl; }
        __syncthreads();
        if (threadIdx.x == 1023) carry_s = carry + woff + x;
        __syncthreads();
    }
    if (threadIdx.x == 0) offs[n] = carry_s;
}

__global__ void scatter_kernel(const int* __restrict__ src, const int* __restrict__ dst, int E,
                               int* __restrict__ cursor, int* __restrict__ srcidx) {
    int i = blockIdx.x * blockDim.x + threadIdx.x;
    if (i < E) {
        int p = atomicAdd(&cursor[dst[i]], 1);
        srcidx[p] = src[i];
    }
}

// ---------------- GEMM (f32, tiled) ----------------
// C[M,N] = A[M,K] @ B[K,N].  BM=128, BN=64, BK=16, 256 threads, 8x4 per thread.
__global__ __launch_bounds__(256) void gemm_f32(const float* __restrict__ A,
                                                const float* __restrict__ B,
                                                float* __restrict__ C,
                                                int M, int N, int K) {
    constexpr int BM = 128, BN = 64, BK = 16;
    __shared__ float As[BK][BM + 4];
    __shared__ float Bs[BK][BN + 4];
    const int tid = threadIdx.x;
    const int tx = tid & 15;   // col group (4 cols each)
    const int ty = tid >> 4;   // row group (8 rows each)
    const int m0 = blockIdx.x * BM;
    const int n0 = blockIdx.y * BN;
    float acc[8][4] = {};
    for (int k0 = 0; k0 < K; k0 += BK) {
        // A tile: 128x16 -> As[k][m]
        #pragma unroll
        for (int p = 0; p < 2; ++p) {
            int r = (tid >> 2) + p * 64;
            int c = (tid & 3) * 4;
            int gr = m0 + r;
            float4 v = make_float4(0.f, 0.f, 0.f, 0.f);
            if (gr < M) v = *(const float4*)&A[(size_t)gr * K + k0 + c];
            As[c + 0][r] = v.x; As[c + 1][r] = v.y; As[c + 2][r] = v.z; As[c + 3][r] = v.w;
        }
        // B tile: 16x64 -> Bs[k][n]
        {
            int r = tid >> 4;
            int c = (tid & 15) * 4;
            float4 v = *(const float4*)&B[(size_t)(k0 + r) * N + n0 + c];
            Bs[r][c + 0] = v.x; Bs[r][c + 1] = v.y; Bs[r][c + 2] = v.z; Bs[r][c + 3] = v.w;
        }
        __syncthreads();
        #pragma unroll
        for (int k = 0; k < BK; ++k) {
            float a[8], b[4];
            #pragma unroll
            for (int i = 0; i < 8; ++i) a[i] = As[k][ty * 8 + i];
            #pragma unroll
            for (int j = 0; j < 4; ++j) b[j] = Bs[k][tx * 4 + j];
            #pragma unroll
            for (int i = 0; i < 8; ++i)
                #pragma unroll
                for (int j = 0; j < 4; ++j)
                    acc[i][j] = fmaf(a[i], b[j], acc[i][j]);
        }
        __syncthreads();
    }
    #pragma unroll
    for (int i = 0; i < 8; ++i) {
        int gr = m0 + ty * 8 + i;
        if (gr < M) {
            float4 v = make_float4(acc[i][0], acc[i][1], acc[i][2], acc[i][3]);
            *(float4*)&C[(size_t)gr * N + n0 + tx * 4] = v;
        }
    }
}

// ---------------- el/er dot products ----------------

// layer0: f[N0][256] viewed as (N0, 4, 64); el over all rows, er over first N1
__global__ __launch_bounds__(256) void elr0_kernel(const float* __restrict__ f,
                                                   const float* __restrict__ al,
                                                   const float* __restrict__ ar,
                                                   float* __restrict__ el,
                                                   float* __restrict__ er) {
    int wave = threadIdx.x >> 6;
    int lane = threadIdx.x & 63;
    int n = blockIdx.x * 4 + wave;
    if (n >= cN0) return;
    const float* row = f + (size_t)n * 256;
    bool isDst = (n < cN1);
    #pragma unroll
    for (int h = 0; h < 4; ++h) {
        float x = row[h * 64 + lane];
        float v = x * al[h * 64 + lane];
        float w = isDst ? x * ar[h * 64 + lane] : 0.f;
        #pragma unroll
        for (int o = 32; o; o >>= 1) { v += __shfl_xor(v, o); w += __shfl_xor(w, o); }
        if (lane == 0) {
            el[n * 4 + h] = v;
            if (isDst) er[n * 4 + h] = w;
        }
    }
}

// layer1: f2[N1][64], single head
__global__ __launch_bounds__(256) void elr1_kernel(const float* __restrict__ f2,
                                                   const float* __restrict__ al,
                                                   const float* __restrict__ ar,
                                                   float* __restrict__ el,
                                                   float* __restrict__ er) {
    int wave = threadIdx.x >> 6;
    int lane = threadIdx.x & 63;
    int n = blockIdx.x * 4 + wave;
    if (n >= cN1) return;
    float x = f2[(size_t)n * 64 + lane];
    float v = x * al[lane];
    float w = (n < cN2) ? x * ar[lane] : 0.f;
    #pragma unroll
    for (int o = 32; o; o >>= 1) { v += __shfl_xor(v, o); w += __shfl_xor(w, o); }
    if (lane == 0) { el[n] = v; if (n < cN2) er[n] = w; }
}

// ---------------- aggregation (edge softmax + message sum) ----------------

__device__ __forceinline__ float lrelu(float x) { return x >= 0.f ? x : SLOPE * x; }

// layer0: one block (4 waves = 4 heads) per dst node; fused +bias, ReLU
__global__ __launch_bounds__(256) void agg0_kernel(const int* __restrict__ offs,
                                                   const int* __restrict__ srcidx,
                                                   const float* __restrict__ el,
                                                   const float* __restrict__ er,
                                                   const float* __restrict__ f,
                                                   const float* __restrict__ bias,
                                                   float* __restrict__ h1) {
    int n = blockIdx.x;
    int h = threadIdx.x >> 6;
    int lane = threadIdx.x & 63;
    int beg = offs[n], end = offs[n + 1];
    float ern = er[n * 4 + h];

    float mmax = -1e30f;
    for (int i = beg + lane; i < end; i += 64) {
        int s = srcidx[i];
        mmax = fmaxf(mmax, lrelu(el[s * 4 + h] + ern));
    }
    #pragma unroll
    for (int o = 32; o; o >>= 1) mmax = fmaxf(mmax, __shfl_xor(mmax, o));

    float ssum = 0.f;
    for (int i = beg + lane; i < end; i += 64) {
        int s = srcidx[i];
        ssum += __expf(lrelu(el[s * 4 + h] + ern) - mmax);
    }
    #pragma unroll
    for (int o = 32; o; o >>= 1) ssum += __shfl_xor(ssum, o);
    float inv = (ssum > 0.f) ? 1.f / ssum : 0.f;

    float acc = 0.f;
    for (int i = beg; i < end; ++i) {
        int s = srcidx[i];
        float p = __expf(lrelu(el[s * 4 + h] + ern) - mmax) * inv;
        acc = fmaf(f[(size_t)s * 256 + h * 64 + lane], p, acc);
    }
    float out = acc + bias[h * 64 + lane];
    h1[(size_t)n * 256 + h * 64 + lane] = out > 0.f ? out : 0.f;
}

// layer1: one wave per dst node (4 nodes/block); fused +bias (no activation)
__global__ __launch_bounds__(256) void agg1_kernel(const int* __restrict__ offs,
                                                   const int* __restrict__ srcidx,
                                                   const float* __restrict__ el,
                                                   const float* __restrict__ er,
                                                   const float* __restrict__ f2,
                                                   const float* __restrict__ bias,
                                                   float* __restrict__ out) {
    int wave = threadIdx.x >> 6;
    int lane = threadIdx.x & 63;
    int n = blockIdx.x * 4 + wave;
    if (n >= cN2) return;
    int beg = offs[n], end = offs[n + 1];
    float ern = er[n];

    float mmax = -1e30f;
    for (int i = beg + lane; i < end; i += 64) {
        mmax = fmaxf(mmax, lrelu(el[srcidx[i]] + ern));
    }
    #pragma unroll
    for (int o = 32; o; o >>= 1) mmax = fmaxf(mmax, __shfl_xor(mmax, o));

    float ssum = 0.f;
    for (int i = beg + lane; i < end; i += 64) {
        ssum += __expf(lrelu(el[srcidx[i]] + ern) - mmax);
    }
    #pragma unroll
    for (int o = 32; o; o >>= 1) ssum += __shfl_xor(ssum, o);
    float inv = (ssum > 0.f) ? 1.f / ssum : 0.f;

    float acc = 0.f;
    for (int i = beg; i < end; ++i) {
        int s = srcidx[i];
        float p = __expf(lrelu(el[s] + ern) - mmax) * inv;
        acc = fmaf(f2[(size_t)s * 64 + lane], p, acc);
    }
    out[(size_t)n * 64 + lane] = acc + bias[lane];
}

// ---------------- launch ----------------

extern "C" void kernel_launch(void* const* d_in, const int* in_sizes, int n_in,
                              void* d_out, int out_size, void* d_ws, size_t ws_size,
                              hipStream_t stream) {
    const float* x      = (const float*)d_in[0];
    const int*   e0_src = (const int*)d_in[1];
    const int*   e0_dst = (const int*)d_in[2];
    const int*   e1_src = (const int*)d_in[3];
    const int*   e1_dst = (const int*)d_in[4];
    const float* W1     = (const float*)d_in[5];
    const float* al1    = (const float*)d_in[6];
    const float* ar1    = (const float*)d_in[7];
    const float* b1     = (const float*)d_in[8];
    const float* W2     = (const float*)d_in[9];
    const float* al2    = (const float*)d_in[10];
    const float* ar2    = (const float*)d_in[11];
    const float* b2     = (const float*)d_in[12];
    float* out = (float*)d_out;

    // workspace bump allocator (256B aligned)
    char* ws = (char*)d_ws;
    size_t off = 0;
    auto alloc = [&](size_t bytes) -> void* {
        void* p = ws + off;
        off = (off + bytes + 255) & ~(size_t)255;
        return p;
    };
    float* f    = (float*)alloc((size_t)cN0 * 256 * 4);   // layer0 projection
    float* h1   = (float*)alloc((size_t)cN1 * 256 * 4);   // layer0 output
    float* f2   = (float*)alloc((size_t)cN1 * 64 * 4);    // layer1 projection
    float* el0  = (float*)alloc((size_t)cN0 * 4 * 4);
    float* er0  = (float*)alloc((size_t)cN1 * 4 * 4);
    float* el2  = (float*)alloc((size_t)cN1 * 4);
    float* er2  = (float*)alloc((size_t)cN2 * 4);
    int* cnt0    = (int*)alloc((size_t)cN1 * 4);
    int* offs0   = (int*)alloc((size_t)(cN1 + 1) * 4);
    int* cursor0 = (int*)alloc((size_t)cN1 * 4);
    int* srcidx0 = (int*)alloc((size_t)cE0 * 4);
    int* cnt1    = (int*)alloc((size_t)cN2 * 4);
    int* offs1   = (int*)alloc((size_t)(cN2 + 1) * 4);
    int* cursor1 = (int*)alloc((size_t)cN2 * 4);
    int* srcidx1 = (int*)alloc((size_t)cE1 * 4);
    (void)ws_size; (void)n_in; (void)in_sizes; (void)out_size;

    // CSR build for both layers
    hipMemsetAsync(cnt0, 0, (size_t)cN1 * 4, stream);
    hipMemsetAsync(cnt1, 0, (size_t)cN2 * 4, stream);
    hist_kernel<<<(cE0 + 255) / 256, 256, 0, stream>>>(e0_dst, cE0, cnt0);
    hist_kernel<<<(cE1 + 255) / 256, 256, 0, stream>>>(e1_dst, cE1, cnt1);
    scan_kernel<<<1, 1024, 0, stream>>>(cnt0, cN1, offs0, cursor0);
    scan_kernel<<<1, 1024, 0, stream>>>(cnt1, cN2, offs1, cursor1);
    scatter_kernel<<<(cE0 + 255) / 256, 256, 0, stream>>>(e0_src, e0_dst, cE0, cursor0, srcidx0);
    scatter_kernel<<<(cE1 + 255) / 256, 256, 0, stream>>>(e1_src, e1_dst, cE1, cursor1, srcidx1);

    // ----- layer 0 -----
    gemm_f32<<<dim3((cN0 + 127) / 128, 256 / 64), 256, 0, stream>>>(x, W1, f, cN0, 256, 256);
    elr0_kernel<<<(cN0 + 3) / 4, 256, 0, stream>>>(f, al1, ar1, el0, er0);
    agg0_kernel<<<cN1, 256, 0, stream>>>(offs0, srcidx0, el0, er0, f, b1, h1);

    // ----- layer 1 -----
    gemm_f32<<<dim3((cN1 + 127) / 128, 1), 256, 0, stream>>>(h1, W2, f2, cN1, 64, 256);
    elr1_kernel<<<(cN1 + 3) / 4, 256, 0, stream>>>(f2, al2, ar2, el2, er2);
    agg1_kernel<<<(cN2 + 3) / 4, 256, 0, stream>>>(offs1, srcidx1, el2, er2, f2, b2, out);
}

// Round 2
// 336.224 us; speedup vs baseline: 1.7813x; 1.7813x over previous
//
#include <hip/hip_runtime.h>
#include <cstddef>
#include <cstdint>

constexpr int cN0 = 100000, cN1 = 50000, cN2 = 25000;
constexpr int cE0 = 400000, cE1 = 200000;
constexpr float SLOPE = 0.2f;

typedef short short8  __attribute__((ext_vector_type(8)));
typedef short short4v __attribute__((ext_vector_type(4)));
typedef float f32x4   __attribute__((ext_vector_type(4)));

__device__ __forceinline__ unsigned short f2bf(float x) {
    union { float f; uint32_t u; } c; c.f = x;
    uint32_t u = c.u + 0x7FFFu + ((c.u >> 16) & 1u);   // RNE
    return (unsigned short)(u >> 16);
}

// ---------------- CSR build ----------------

__global__ void hist_kernel(const int* __restrict__ dst, int E, int* __restrict__ cnt) {
    int i = blockIdx.x * blockDim.x + threadIdx.x;
    if (i < E) atomicAdd(&cnt[dst[i]], 1);
}

__global__ __launch_bounds__(256) void chunk_sum_kernel(const int* __restrict__ cnt, int n,
                                                        int* __restrict__ bsum) {
    int i = blockIdx.x * 256 + threadIdx.x;
    int v = (i < n) ? cnt[i] : 0;
    #pragma unroll
    for (int o = 32; o; o >>= 1) v += __shfl_xor(v, o);
    __shared__ int ws[4];
    if ((threadIdx.x & 63) == 0) ws[threadIdx.x >> 6] = v;
    __syncthreads();
    if (threadIdx.x == 0) bsum[blockIdx.x] = ws[0] + ws[1] + ws[2] + ws[3];
}

__device__ __forceinline__ int block_exscan(int v, int& total) {
    int lane = threadIdx.x & 63, w = threadIdx.x >> 6;
    int x = v;
    #pragma unroll
    for (int o = 1; o < 64; o <<= 1) { int t = __shfl_up(x, o); if (lane >= o) x += t; }
    __shared__ int ws[4];
    if (lane == 63) ws[w] = x;
    __syncthreads();
    int add = 0;
    #pragma unroll
    for (int i = 0; i < 4; ++i) if (i < w) add += ws[i];
    total = ws[0] + ws[1] + ws[2] + ws[3];
    return add + x - v;
}

// single block; nblk <= 256
__global__ __launch_bounds__(256) void top_scan_kernel(const int* __restrict__ bsum, int nblk,
                                                       int* __restrict__ boff, int* __restrict__ total_out) {
    int i = threadIdx.x;
    int v = (i < nblk) ? bsum[i] : 0;
    int tot; int e = block_exscan(v, tot);
    if (i < nblk) boff[i] = e;
    if (i == 0) *total_out = tot;
}

__global__ __launch_bounds__(256) void chunk_scan_kernel(const int* __restrict__ cnt, int n,
                                                         const int* __restrict__ boff,
                                                         int* __restrict__ offs, int* __restrict__ cursor) {
    int i = blockIdx.x * 256 + threadIdx.x;
    int v = (i < n) ? cnt[i] : 0;
    int tot; int e = block_exscan(v, tot) + boff[blockIdx.x];
    if (i < n) { offs[i] = e; cursor[i] = e; }
}

__global__ void scatter_kernel(const int* __restrict__ src, const int* __restrict__ dst, int E,
                               int* __restrict__ cursor, int* __restrict__ srcidx) {
    int i = blockIdx.x * blockDim.x + threadIdx.x;
    if (i < E) {
        int p = atomicAdd(&cursor[dst[i]], 1);
        srcidx[p] = src[i];
    }
}

// ---------------- weight transpose to bf16 ----------------
// B [K][N] f32 -> BT [N][K] bf16
__global__ __launch_bounds__(256) void bf16_transpose_kernel(const float* __restrict__ B,
                                                             short* __restrict__ BT, int K, int N) {
    int i = blockIdx.x * 256 + threadIdx.x;
    if (i >= K * N) return;
    int k = i / N, n = i - k * N;
    BT[(size_t)n * K + k] = (short)f2bf(B[i]);
}

// ---------------- bf16 MFMA GEMM with fused el/er epilogue ----------------
// C[M, nh*64] = A[M,K] @ B[K, nh*64];  el[r,h] = C[r, h*64:]·al[h], er likewise (rows < erN).
// Each wave covers exactly one 64-col head (BN/WC == 64).
template<int BM, int BN, int WR, int WC>
__global__ __launch_bounds__(256) void gemm_bf16_fused(
    const float* __restrict__ A, const short* __restrict__ BT,
    float* __restrict__ C,
    const float* __restrict__ al, const float* __restrict__ ar,
    float* __restrict__ el, float* __restrict__ er,
    int M, int K, int nh, int erN)
{
    constexpr int BK = 32;
    constexpr int PITCH = BK + 8;          // bf16 elems/row (80 B) -> conflict-free b128 reads
    constexpr int MI = BM / WR / 16;
    constexpr int NI = BN / WC / 16;
    constexpr int AIT = BM * 8 / 256;      // float4 slots per thread
    constexpr int BIT = BN * 4 / 256;      // short8 slots per thread
    static_assert(NI * 16 * WC == BN && MI * 16 * WR == BM, "tile mismatch");

    __shared__ short As[BM * PITCH];
    __shared__ short Bs[BN * PITCH];

    const int tid = threadIdx.x;
    const int w = tid >> 6;
    const int lane = tid & 63;
    const int ln = lane & 15;
    const int kg = lane >> 4;
    const int wr = w / WC;
    const int wc = w % WC;
    const int m0 = blockIdx.x * BM;
    const int n0 = blockIdx.y * BN;
    const int N = nh * 64;

    f32x4 acc[MI][NI];
    #pragma unroll
    for (int mi = 0; mi < MI; ++mi)
        #pragma unroll
        for (int ni = 0; ni < NI; ++ni)
            #pragma unroll
            for (int j = 0; j < 4; ++j) acc[mi][ni][j] = 0.f;

    float4 areg[AIT];
    short8 breg[BIT];

    auto loadA = [&](int k0) {
        #pragma unroll
        for (int p = 0; p < AIT; ++p) {
            int slot = tid + p * 256;
            int r = slot >> 3;
            int kq = (slot & 7) * 4;
            int gr = m0 + r;
            float4 v = make_float4(0.f, 0.f, 0.f, 0.f);
            if (gr < M) v = *(const float4*)&A[(size_t)gr * K + k0 + kq];
            areg[p] = v;
        }
    };
    auto loadB = [&](int k0) {
        #pragma unroll
        for (int p = 0; p < BIT; ++p) {
            int slot = tid + p * 256;
            int r = slot >> 2;
            int kq = (slot & 3) * 8;
            breg[p] = *(const short8*)&BT[(size_t)(n0 + r) * K + k0 + kq];
        }
    };
    auto writeLDS = [&]() {
        #pragma unroll
        for (int p = 0; p < AIT; ++p) {
            int slot = tid + p * 256;
            int r = slot >> 3;
            int kq = (slot & 7) * 4;
            short4v s;
            s[0] = (short)f2bf(areg[p].x); s[1] = (short)f2bf(areg[p].y);
            s[2] = (short)f2bf(areg[p].z); s[3] = (short)f2bf(areg[p].w);
            *(short4v*)&As[r * PITCH + kq] = s;
        }
        #pragma unroll
        for (int p = 0; p < BIT; ++p) {
            int slot = tid + p * 256;
            int r = slot >> 2;
            int kq = (slot & 3) * 8;
            *(short8*)&Bs[r * PITCH + kq] = breg[p];
        }
    };

    loadA(0); loadB(0);
    const int T = K / BK;
    for (int t = 0; t < T; ++t) {
        writeLDS();
        __syncthreads();
        if (t + 1 < T) { loadA((t + 1) * BK); loadB((t + 1) * BK); }
        short8 af[MI], bf[NI];
        #pragma unroll
        for (int mi = 0; mi < MI; ++mi)
            af[mi] = *(const short8*)&As[(wr * MI * 16 + mi * 16 + ln) * PITCH + kg * 8];
        #pragma unroll
        for (int ni = 0; ni < NI; ++ni)
            bf[ni] = *(const short8*)&Bs[(wc * NI * 16 + ni * 16 + ln) * PITCH + kg * 8];
        #pragma unroll
        for (int mi = 0; mi < MI; ++mi)
            #pragma unroll
            for (int ni = 0; ni < NI; ++ni)
                acc[mi][ni] = __builtin_amdgcn_mfma_f32_16x16x32_bf16(af[mi], bf[ni], acc[mi][ni], 0, 0, 0);
        __syncthreads();
    }

    // epilogue: C store + fused el/er
    const int h = (n0 + wc * NI * 16) >> 6;
    float alv[NI], arv[NI];
    #pragma unroll
    for (int ni = 0; ni < NI; ++ni) {
        alv[ni] = al[h * 64 + ni * 16 + ln];
        arv[ni] = ar[h * 64 + ni * 16 + ln];
    }
    #pragma unroll
    for (int mi = 0; mi < MI; ++mi) {
        float pl[4] = {0, 0, 0, 0}, pr[4] = {0, 0, 0, 0};
        #pragma unroll
        for (int ni = 0; ni < NI; ++ni)
            #pragma unroll
            for (int j = 0; j < 4; ++j) {
                float v = acc[mi][ni][j];
                pl[j] += v * alv[ni];
                pr[j] += v * arv[ni];
            }
        #pragma unroll
        for (int j = 0; j < 4; ++j)
            #pragma unroll
            for (int o = 1; o < 16; o <<= 1) {
                pl[j] += __shfl_xor(pl[j], o);
                pr[j] += __shfl_xor(pr[j], o);
            }
        #pragma unroll
        for (int j = 0; j < 4; ++j) {
            int row = m0 + wr * MI * 16 + mi * 16 + kg * 4 + j;
            if (row < M) {
                #pragma unroll
                for (int ni = 0; ni < NI; ++ni)
                    C[(size_t)row * N + n0 + wc * NI * 16 + ni * 16 + ln] = acc[mi][ni][j];
                if (ln == 0) {
                    el[row * nh + h] = pl[j];
                    if (row < erN) er[row * nh + h] = pr[j];
                }
            }
        }
    }
}

// ---------------- aggregation (edge softmax + message sum) ----------------

__device__ __forceinline__ float lrelu(float x) { return x >= 0.f ? x : SLOPE * x; }

__global__ __launch_bounds__(256) void agg0_kernel(const int* __restrict__ offs,
                                                   const int* __restrict__ srcidx,
                                                   const float* __restrict__ el,
                                                   const float* __restrict__ er,
                                                   const float* __restrict__ f,
                                                   const float* __restrict__ bias,
                                                   float* __restrict__ h1) {
    int n = blockIdx.x;
    int h = threadIdx.x >> 6;
    int lane = threadIdx.x & 63;
    int beg = offs[n], end = offs[n + 1];
    float ern = er[n * 4 + h];

    float mmax = -1e30f;
    for (int i = beg + lane; i < end; i += 64) {
        int s = srcidx[i];
        mmax = fmaxf(mmax, lrelu(el[s * 4 + h] + ern));
    }
    #pragma unroll
    for (int o = 32; o; o >>= 1) mmax = fmaxf(mmax, __shfl_xor(mmax, o));

    float ssum = 0.f;
    for (int i = beg + lane; i < end; i += 64) {
        int s = srcidx[i];
        ssum += __expf(lrelu(el[s * 4 + h] + ern) - mmax);
    }
    #pragma unroll
    for (int o = 32; o; o >>= 1) ssum += __shfl_xor(ssum, o);
    float inv = (ssum > 0.f) ? 1.f / ssum : 0.f;

    float acc = 0.f;
    for (int i = beg; i < end; ++i) {
        int s = srcidx[i];
        float p = __expf(lrelu(el[s * 4 + h] + ern) - mmax) * inv;
        acc = fmaf(f[(size_t)s * 256 + h * 64 + lane], p, acc);
    }
    float out = acc + bias[h * 64 + lane];
    h1[(size_t)n * 256 + h * 64 + lane] = out > 0.f ? out : 0.f;
}

__global__ __launch_bounds__(256) void agg1_kernel(const int* __restrict__ offs,
                                                   const int* __restrict__ srcidx,
                                                   const float* __restrict__ el,
                                                   const float* __restrict__ er,
                                                   const float* __restrict__ f2,
                                                   const float* __restrict__ bias,
                                                   float* __restrict__ out) {
    int wave = threadIdx.x >> 6;
    int lane = threadIdx.x & 63;
    int n = blockIdx.x * 4 + wave;
    if (n >= cN2) return;
    int beg = offs[n], end = offs[n + 1];
    float ern = er[n];

    float mmax = -1e30f;
    for (int i = beg + lane; i < end; i += 64) {
        mmax = fmaxf(mmax, lrelu(el[srcidx[i]] + ern));
    }
    #pragma unroll
    for (int o = 32; o; o >>= 1) mmax = fmaxf(mmax, __shfl_xor(mmax, o));

    float ssum = 0.f;
    for (int i = beg + lane; i < end; i += 64) {
        ssum += __expf(lrelu(el[srcidx[i]] + ern) - mmax);
    }
    #pragma unroll
    for (int o = 32; o; o >>= 1) ssum += __shfl_xor(ssum, o);
    float inv = (ssum > 0.f) ? 1.f / ssum : 0.f;

    float acc = 0.f;
    for (int i = beg; i < end; ++i) {
        int s = srcidx[i];
        float p = __expf(lrelu(el[s] + ern) - mmax) * inv;
        acc = fmaf(f2[(size_t)s * 64 + lane], p, acc);
    }
    out[(size_t)n * 64 + lane] = acc + bias[lane];
}

// ---------------- launch ----------------

extern "C" void kernel_launch(void* const* d_in, const int* in_sizes, int n_in,
                              void* d_out, int out_size, void* d_ws, size_t ws_size,
                              hipStream_t stream) {
    const float* x      = (const float*)d_in[0];
    const int*   e0_src = (const int*)d_in[1];
    const int*   e0_dst = (const int*)d_in[2];
    const int*   e1_src = (const int*)d_in[3];
    const int*   e1_dst = (const int*)d_in[4];
    const float* W1     = (const float*)d_in[5];
    const float* al1    = (const float*)d_in[6];
    const float* ar1    = (const float*)d_in[7];
    const float* b1     = (const float*)d_in[8];
    const float* W2     = (const float*)d_in[9];
    const float* al2    = (const float*)d_in[10];
    const float* ar2    = (const float*)d_in[11];
    const float* b2     = (const float*)d_in[12];
    float* out = (float*)d_out;

    char* ws = (char*)d_ws;
    size_t off = 0;
    auto alloc = [&](size_t bytes) -> void* {
        void* p = ws + off;
        off = (off + bytes + 255) & ~(size_t)255;
        return p;
    };
    float* f    = (float*)alloc((size_t)cN0 * 256 * 4);
    float* h1   = (float*)alloc((size_t)cN1 * 256 * 4);
    float* f2   = (float*)alloc((size_t)cN1 * 64 * 4);
    float* el0  = (float*)alloc((size_t)cN0 * 4 * 4);
    float* er0  = (float*)alloc((size_t)cN1 * 4 * 4);
    float* el2  = (float*)alloc((size_t)cN1 * 4);
    float* er2  = (float*)alloc((size_t)cN2 * 4);
    short* bt1  = (short*)alloc((size_t)256 * 256 * 2);
    short* bt2  = (short*)alloc((size_t)64 * 256 * 2);
    int* cnt0    = (int*)alloc((size_t)cN1 * 4);
    int* offs0   = (int*)alloc((size_t)(cN1 + 1) * 4);
    int* cursor0 = (int*)alloc((size_t)cN1 * 4);
    int* srcidx0 = (int*)alloc((size_t)cE0 * 4);
    int* cnt1    = (int*)alloc((size_t)cN2 * 4);
    int* offs1   = (int*)alloc((size_t)(cN2 + 1) * 4);
    int* cursor1 = (int*)alloc((size_t)cN2 * 4);
    int* srcidx1 = (int*)alloc((size_t)cE1 * 4);
    int* bsum0   = (int*)alloc(256 * 4);
    int* boff0   = (int*)alloc(256 * 4);
    int* bsum1   = (int*)alloc(256 * 4);
    int* boff1   = (int*)alloc(256 * 4);
    (void)ws_size; (void)n_in; (void)in_sizes; (void)out_size;

    const int nblk0 = (cN1 + 255) / 256;   // 196
    const int nblk1 = (cN2 + 255) / 256;   // 98

    // CSR build
    hipMemsetAsync(cnt0, 0, (size_t)cN1 * 4, stream);
    hipMemsetAsync(cnt1, 0, (size_t)cN2 * 4, stream);
    hist_kernel<<<(cE0 + 255) / 256, 256, 0, stream>>>(e0_dst, cE0, cnt0);
    hist_kernel<<<(cE1 + 255) / 256, 256, 0, stream>>>(e1_dst, cE1, cnt1);
    chunk_sum_kernel<<<nblk0, 256, 0, stream>>>(cnt0, cN1, bsum0);
    chunk_sum_kernel<<<nblk1, 256, 0, stream>>>(cnt1, cN2, bsum1);
    top_scan_kernel<<<1, 256, 0, stream>>>(bsum0, nblk0, boff0, offs0 + cN1);
    top_scan_kernel<<<1, 256, 0, stream>>>(bsum1, nblk1, boff1, offs1 + cN2);
    chunk_scan_kernel<<<nblk0, 256, 0, stream>>>(cnt0, cN1, boff0, offs0, cursor0);
    chunk_scan_kernel<<<nblk1, 256, 0, stream>>>(cnt1, cN2, boff1, offs1, cursor1);
    scatter_kernel<<<(cE0 + 255) / 256, 256, 0, stream>>>(e0_src, e0_dst, cE0, cursor0, srcidx0);
    scatter_kernel<<<(cE1 + 255) / 256, 256, 0, stream>>>(e1_src, e1_dst, cE1, cursor1, srcidx1);

    // weights -> bf16 transposed
    bf16_transpose_kernel<<<(256 * 256 + 255) / 256, 256, 0, stream>>>(W1, bt1, 256, 256);
    bf16_transpose_kernel<<<(256 * 64 + 255) / 256, 256, 0, stream>>>(W2, bt2, 256, 64);

    // ----- layer 0 -----
    gemm_bf16_fused<128, 128, 2, 2><<<dim3((cN0 + 127) / 128, 2), 256, 0, stream>>>(
        x, bt1, f, al1, ar1, el0, er0, cN0, 256, 4, cN1);
    agg0_kernel<<<cN1, 256, 0, stream>>>(offs0, srcidx0, el0, er0, f, b1, h1);

    // ----- layer 1 -----
    gemm_bf16_fused<128, 64, 4, 1><<<dim3((cN1 + 127) / 128, 1), 256, 0, stream>>>(
        h1, bt2, f2, al2, ar2, el2, er2, cN1, 256, 1, cN2);
    agg1_kernel<<<(cN2 + 3) / 4, 256, 0, stream>>>(offs1, srcidx1, el2, er2, f2, b2, out);
}

// Round 3
// 245.149 us; speedup vs baseline: 2.4430x; 1.3715x over previous
//
#include <hip/hip_runtime.h>
#include <cstddef>
#include <cstdint>

constexpr int cN0 = 100000, cN1 = 50000, cN2 = 25000;
constexpr int cE0 = 400000, cE1 = 200000;
constexpr float SLOPE = 0.2f;

typedef short short8  __attribute__((ext_vector_type(8)));
typedef short short4v __attribute__((ext_vector_type(4)));
typedef float f32x4   __attribute__((ext_vector_type(4)));

__device__ __forceinline__ unsigned short f2bf(float x) {
    union { float f; uint32_t u; } c; c.f = x;
    uint32_t u = c.u + 0x7FFFu + ((c.u >> 16) & 1u);   // RNE
    return (unsigned short)(u >> 16);
}
__device__ __forceinline__ float bf2f(unsigned short u) {
    union { uint32_t u; float f; } c; c.u = ((uint32_t)u) << 16; return c.f;
}
__device__ __forceinline__ float lrelu(float x) { return x >= 0.f ? x : SLOPE * x; }

// ---------------- CSR build ----------------

__global__ void hist_kernel(const int* __restrict__ dst, int E, int* __restrict__ cnt) {
    int i = blockIdx.x * blockDim.x + threadIdx.x;
    if (i < E) atomicAdd(&cnt[dst[i]], 1);
}

__global__ __launch_bounds__(256) void chunk_sum_kernel(const int* __restrict__ cnt, int n,
                                                        int* __restrict__ bsum) {
    int i = blockIdx.x * 256 + threadIdx.x;
    int v = (i < n) ? cnt[i] : 0;
    #pragma unroll
    for (int o = 32; o; o >>= 1) v += __shfl_xor(v, o);
    __shared__ int ws[4];
    if ((threadIdx.x & 63) == 0) ws[threadIdx.x >> 6] = v;
    __syncthreads();
    if (threadIdx.x == 0) bsum[blockIdx.x] = ws[0] + ws[1] + ws[2] + ws[3];
}

__device__ __forceinline__ int block_exscan(int v, int& total) {
    int lane = threadIdx.x & 63, w = threadIdx.x >> 6;
    int x = v;
    #pragma unroll
    for (int o = 1; o < 64; o <<= 1) { int t = __shfl_up(x, o); if (lane >= o) x += t; }
    __shared__ int ws[4];
    if (lane == 63) ws[w] = x;
    __syncthreads();
    int add = 0;
    #pragma unroll
    for (int i = 0; i < 4; ++i) if (i < w) add += ws[i];
    total = ws[0] + ws[1] + ws[2] + ws[3];
    return add + x - v;
}

__global__ __launch_bounds__(256) void top_scan_kernel(const int* __restrict__ bsum, int nblk,
                                                       int* __restrict__ boff, int* __restrict__ total_out) {
    int i = threadIdx.x;
    int v = (i < nblk) ? bsum[i] : 0;
    int tot; int e = block_exscan(v, tot);
    if (i < nblk) boff[i] = e;
    if (i == 0) *total_out = tot;
}

__global__ __launch_bounds__(256) void chunk_scan_kernel(const int* __restrict__ cnt, int n,
                                                         const int* __restrict__ boff,
                                                         int* __restrict__ offs, int* __restrict__ cursor) {
    int i = blockIdx.x * 256 + threadIdx.x;
    int v = (i < n) ? cnt[i] : 0;
    int tot; int e = block_exscan(v, tot) + boff[blockIdx.x];
    if (i < n) { offs[i] = e; cursor[i] = e; }
}

__global__ void scatter_kernel(const int* __restrict__ src, const int* __restrict__ dst, int E,
                               int* __restrict__ cursor, int* __restrict__ srcidx) {
    int i = blockIdx.x * blockDim.x + threadIdx.x;
    if (i < E) {
        int p = atomicAdd(&cursor[dst[i]], 1);
        srcidx[p] = src[i];
    }
}

// ---------------- weight transpose to bf16 ----------------
__global__ __launch_bounds__(256) void bf16_transpose_kernel(const float* __restrict__ B,
                                                             short* __restrict__ BT, int K, int N) {
    int i = blockIdx.x * 256 + threadIdx.x;
    if (i >= K * N) return;
    int k = i / N, n = i - k * N;
    BT[(size_t)n * K + k] = (short)f2bf(B[i]);
}

// ---------------- bf16 MFMA GEMM with fused el/er epilogue ----------------
// C[M, nh*64] = A[M,K] @ B; el[r,h] = C row · al[h]; er likewise for rows < erN.
// ABF: A is bf16 (row-major, stride K). C stored as bf16.
template<int BM, int BN, int WR, int WC, bool ABF>
__global__ __launch_bounds__(256) void gemm_bf16_fused(
    const void* __restrict__ Av, const short* __restrict__ BT,
    unsigned short* __restrict__ C,
    const float* __restrict__ al, const float* __restrict__ ar,
    float* __restrict__ el, float* __restrict__ er,
    int M, int K, int nh, int erN)
{
    constexpr int BK = 32;
    constexpr int PITCH = BK + 8;
    constexpr int MI = BM / WR / 16;
    constexpr int NI = BN / WC / 16;
    constexpr int AIT  = BM * 8 / 256;   // float4 slots (f32 A)
    constexpr int AITB = BM * 4 / 256;   // short8 slots (bf16 A)
    constexpr int BIT  = BN * 4 / 256;   // short8 slots
    static_assert(NI * 16 * WC == BN && MI * 16 * WR == BM, "tile mismatch");

    __shared__ short As[BM * PITCH];
    __shared__ short Bs[BN * PITCH];

    const int tid = threadIdx.x;
    const int w = tid >> 6;
    const int lane = tid & 63;
    const int ln = lane & 15;
    const int kg = lane >> 4;
    const int wr = w / WC;
    const int wc = w % WC;
    const int m0 = blockIdx.x * BM;
    const int n0 = blockIdx.y * BN;
    const int N = nh * 64;

    f32x4 acc[MI][NI];
    #pragma unroll
    for (int mi = 0; mi < MI; ++mi)
        #pragma unroll
        for (int ni = 0; ni < NI; ++ni)
            #pragma unroll
            for (int j = 0; j < 4; ++j) acc[mi][ni][j] = 0.f;

    float4 areg[AIT];
    short8 aregb[AITB];
    short8 breg[BIT];

    auto loadA = [&](int k0) {
        if constexpr (ABF) {
            const unsigned short* A = (const unsigned short*)Av;
            #pragma unroll
            for (int p = 0; p < AITB; ++p) {
                int slot = tid + p * 256;
                int r = slot >> 2;
                int kq = (slot & 3) * 8;
                int gr = m0 + r;
                short8 v = {};
                if (gr < M) v = *(const short8*)&A[(size_t)gr * K + k0 + kq];
                aregb[p] = v;
            }
        } else {
            const float* A = (const float*)Av;
            #pragma unroll
            for (int p = 0; p < AIT; ++p) {
                int slot = tid + p * 256;
                int r = slot >> 3;
                int kq = (slot & 7) * 4;
                int gr = m0 + r;
                float4 v = make_float4(0.f, 0.f, 0.f, 0.f);
                if (gr < M) v = *(const float4*)&A[(size_t)gr * K + k0 + kq];
                areg[p] = v;
            }
        }
    };
    auto loadB = [&](int k0) {
        #pragma unroll
        for (int p = 0; p < BIT; ++p) {
            int slot = tid + p * 256;
            int r = slot >> 2;
            int kq = (slot & 3) * 8;
            breg[p] = *(const short8*)&BT[(size_t)(n0 + r) * K + k0 + kq];
        }
    };
    auto writeLDS = [&]() {
        if constexpr (ABF) {
            #pragma unroll
            for (int p = 0; p < AITB; ++p) {
                int slot = tid + p * 256;
                int r = slot >> 2;
                int kq = (slot & 3) * 8;
                *(short8*)&As[r * PITCH + kq] = aregb[p];
            }
        } else {
            #pragma unroll
            for (int p = 0; p < AIT; ++p) {
                int slot = tid + p * 256;
                int r = slot >> 3;
                int kq = (slot & 7) * 4;
                short4v s;
                s[0] = (short)f2bf(areg[p].x); s[1] = (short)f2bf(areg[p].y);
                s[2] = (short)f2bf(areg[p].z); s[3] = (short)f2bf(areg[p].w);
                *(short4v*)&As[r * PITCH + kq] = s;
            }
        }
        #pragma unroll
        for (int p = 0; p < BIT; ++p) {
            int slot = tid + p * 256;
            int r = slot >> 2;
            int kq = (slot & 3) * 8;
            *(short8*)&Bs[r * PITCH + kq] = breg[p];
        }
    };

    loadA(0); loadB(0);
    const int T = K / BK;
    for (int t = 0; t < T; ++t) {
        writeLDS();
        __syncthreads();
        if (t + 1 < T) { loadA((t + 1) * BK); loadB((t + 1) * BK); }
        short8 af[MI], bf[NI];
        #pragma unroll
        for (int mi = 0; mi < MI; ++mi)
            af[mi] = *(const short8*)&As[(wr * MI * 16 + mi * 16 + ln) * PITCH + kg * 8];
        #pragma unroll
        for (int ni = 0; ni < NI; ++ni)
            bf[ni] = *(const short8*)&Bs[(wc * NI * 16 + ni * 16 + ln) * PITCH + kg * 8];
        #pragma unroll
        for (int mi = 0; mi < MI; ++mi)
            #pragma unroll
            for (int ni = 0; ni < NI; ++ni)
                acc[mi][ni] = __builtin_amdgcn_mfma_f32_16x16x32_bf16(af[mi], bf[ni], acc[mi][ni], 0, 0, 0);
        __syncthreads();
    }

    const int h = (n0 + wc * NI * 16) >> 6;
    float alv[NI], arv[NI];
    #pragma unroll
    for (int ni = 0; ni < NI; ++ni) {
        alv[ni] = al[h * 64 + ni * 16 + ln];
        arv[ni] = ar[h * 64 + ni * 16 + ln];
    }
    #pragma unroll
    for (int mi = 0; mi < MI; ++mi) {
        float pl[4] = {0, 0, 0, 0}, pr[4] = {0, 0, 0, 0};
        #pragma unroll
        for (int ni = 0; ni < NI; ++ni)
            #pragma unroll
            for (int j = 0; j < 4; ++j) {
                float v = acc[mi][ni][j];
                pl[j] += v * alv[ni];
                pr[j] += v * arv[ni];
            }
        #pragma unroll
        for (int j = 0; j < 4; ++j)
            #pragma unroll
            for (int o = 1; o < 16; o <<= 1) {
                pl[j] += __shfl_xor(pl[j], o);
                pr[j] += __shfl_xor(pr[j], o);
            }
        #pragma unroll
        for (int j = 0; j < 4; ++j) {
            int row = m0 + wr * MI * 16 + mi * 16 + kg * 4 + j;
            if (row < M) {
                #pragma unroll
                for (int ni = 0; ni < NI; ++ni)
                    C[(size_t)row * N + n0 + wc * NI * 16 + ni * 16 + ln] = f2bf(acc[mi][ni][j]);
                if (ln == 0) {
                    el[row * nh + h] = pl[j];
                    if (row < erN) er[row * nh + h] = pr[j];
                }
            }
        }
    }
}

// ---------------- aggregation ----------------

// layer0: one wave per dst node. Pass A: online max+sum, 16 edges x 4 heads parallel.
// Pass B: full bf16 row gather (uint2/lane = 4 elems), all heads at once.
__global__ __launch_bounds__(256) void agg0_kernel(const int* __restrict__ offs,
                                                   const int* __restrict__ srcidx,
                                                   const float* __restrict__ el,
                                                   const float* __restrict__ er,
                                                   const unsigned short* __restrict__ fb,
                                                   const float* __restrict__ bias,
                                                   unsigned short* __restrict__ h1b) {
    int w = threadIdx.x >> 6, lane = threadIdx.x & 63;
    int n = blockIdx.x * 4 + w;
    if (n >= cN1) return;
    int beg = offs[n], end = offs[n + 1];

    int h4 = lane & 3, sub = lane >> 2;
    float erA = er[n * 4 + h4];
    float m = -1e30f, s = 0.f;
    for (int i = beg + sub; i < end; i += 16) {
        int sv = srcidx[i];
        float e = lrelu(el[sv * 4 + h4] + erA);
        if (e > m) { s = s * __expf(m - e) + 1.f; m = e; }
        else s += __expf(e - m);
    }
    #pragma unroll
    for (int o = 4; o < 64; o <<= 1) {
        float m2 = __shfl_xor(m, o), s2 = __shfl_xor(s, o);
        float M = fmaxf(m, m2);
        s = s * __expf(m - M) + s2 * __expf(m2 - M);
        m = M;
    }
    float inv = (s > 0.f) ? 1.f / s : 0.f;

    int hB = lane >> 4;
    float mB = __shfl(m, hB);
    float invB = __shfl(inv, hB);
    float erB = __shfl(erA, hB);

    float a0 = 0.f, a1 = 0.f, a2 = 0.f, a3 = 0.f;
    for (int i = beg; i < end; ++i) {
        int sv = srcidx[i];
        float e = lrelu(el[sv * 4 + hB] + erB);
        float p = __expf(e - mB) * invB;
        uint2 v = *(const uint2*)&fb[(size_t)sv * 256 + lane * 4];
        a0 = fmaf(bf2f((unsigned short)(v.x & 0xffff)), p, a0);
        a1 = fmaf(bf2f((unsigned short)(v.x >> 16)),    p, a1);
        a2 = fmaf(bf2f((unsigned short)(v.y & 0xffff)), p, a2);
        a3 = fmaf(bf2f((unsigned short)(v.y >> 16)),    p, a3);
    }
    float4 b = *(const float4*)&bias[lane * 4];
    float o0 = a0 + b.x, o1 = a1 + b.y, o2 = a2 + b.z, o3 = a3 + b.w;
    short4v r;
    r[0] = (short)f2bf(o0 > 0.f ? o0 : 0.f);
    r[1] = (short)f2bf(o1 > 0.f ? o1 : 0.f);
    r[2] = (short)f2bf(o2 > 0.f ? o2 : 0.f);
    r[3] = (short)f2bf(o3 > 0.f ? o3 : 0.f);
    *(short4v*)&h1b[(size_t)n * 256 + lane * 4] = r;
}

// layer1: one wave per dst node, single head, bf16 f2 gather.
__global__ __launch_bounds__(256) void agg1_kernel(const int* __restrict__ offs,
                                                   const int* __restrict__ srcidx,
                                                   const float* __restrict__ el,
                                                   const float* __restrict__ er,
                                                   const unsigned short* __restrict__ f2b,
                                                   const float* __restrict__ bias,
                                                   float* __restrict__ out) {
    int w = threadIdx.x >> 6, lane = threadIdx.x & 63;
    int n = blockIdx.x * 4 + w;
    if (n >= cN2) return;
    int beg = offs[n], end = offs[n + 1];
    float ern = er[n];

    float m = -1e30f, s = 0.f;
    for (int i = beg + lane; i < end; i += 64) {
        float e = lrelu(el[srcidx[i]] + ern);
        if (e > m) { s = s * __expf(m - e) + 1.f; m = e; }
        else s += __expf(e - m);
    }
    #pragma unroll
    for (int o = 1; o < 64; o <<= 1) {
        float m2 = __shfl_xor(m, o), s2 = __shfl_xor(s, o);
        float M = fmaxf(m, m2);
        s = s * __expf(m - M) + s2 * __expf(m2 - M);
        m = M;
    }
    float inv = (s > 0.f) ? 1.f / s : 0.f;

    float acc = 0.f;
    for (int i = beg; i < end; ++i) {
        int sv = srcidx[i];
        float e = lrelu(el[sv] + ern);
        float p = __expf(e - m) * inv;
        acc = fmaf(bf2f(f2b[(size_t)sv * 64 + lane]), p, acc);
    }
    out[(size_t)n * 64 + lane] = acc + bias[lane];
}

// ---------------- launch ----------------

extern "C" void kernel_launch(void* const* d_in, const int* in_sizes, int n_in,
                              void* d_out, int out_size, void* d_ws, size_t ws_size,
                              hipStream_t stream) {
    const float* x      = (const float*)d_in[0];
    const int*   e0_src = (const int*)d_in[1];
    const int*   e0_dst = (const int*)d_in[2];
    const int*   e1_src = (const int*)d_in[3];
    const int*   e1_dst = (const int*)d_in[4];
    const float* W1     = (const float*)d_in[5];
    const float* al1    = (const float*)d_in[6];
    const float* ar1    = (const float*)d_in[7];
    const float* b1     = (const float*)d_in[8];
    const float* W2     = (const float*)d_in[9];
    const float* al2    = (const float*)d_in[10];
    const float* ar2    = (const float*)d_in[11];
    const float* b2     = (const float*)d_in[12];
    float* out = (float*)d_out;

    char* ws = (char*)d_ws;
    size_t off = 0;
    auto alloc = [&](size_t bytes) -> void* {
        void* p = ws + off;
        off = (off + bytes + 255) & ~(size_t)255;
        return p;
    };
    unsigned short* fb  = (unsigned short*)alloc((size_t)cN0 * 256 * 2);
    unsigned short* h1b = (unsigned short*)alloc((size_t)cN1 * 256 * 2);
    unsigned short* f2b = (unsigned short*)alloc((size_t)cN1 * 64 * 2);
    float* el0  = (float*)alloc((size_t)cN0 * 4 * 4);
    float* er0  = (float*)alloc((size_t)cN1 * 4 * 4);
    float* el2  = (float*)alloc((size_t)cN1 * 4);
    float* er2  = (float*)alloc((size_t)cN2 * 4);
    short* bt1  = (short*)alloc((size_t)256 * 256 * 2);
    short* bt2  = (short*)alloc((size_t)64 * 256 * 2);
    int* cnt0    = (int*)alloc((size_t)cN1 * 4);
    int* offs0   = (int*)alloc((size_t)(cN1 + 1) * 4);
    int* cursor0 = (int*)alloc((size_t)cN1 * 4);
    int* srcidx0 = (int*)alloc((size_t)cE0 * 4);
    int* cnt1    = (int*)alloc((size_t)cN2 * 4);
    int* offs1   = (int*)alloc((size_t)(cN2 + 1) * 4);
    int* cursor1 = (int*)alloc((size_t)cN2 * 4);
    int* srcidx1 = (int*)alloc((size_t)cE1 * 4);
    int* bsum0   = (int*)alloc(256 * 4);
    int* boff0   = (int*)alloc(256 * 4);
    int* bsum1   = (int*)alloc(256 * 4);
    int* boff1   = (int*)alloc(256 * 4);
    (void)ws_size; (void)n_in; (void)in_sizes; (void)out_size;

    const int nblk0 = (cN1 + 255) / 256;
    const int nblk1 = (cN2 + 255) / 256;

    hipMemsetAsync(cnt0, 0, (size_t)cN1 * 4, stream);
    hipMemsetAsync(cnt1, 0, (size_t)cN2 * 4, stream);
    hist_kernel<<<(cE0 + 255) / 256, 256, 0, stream>>>(e0_dst, cE0, cnt0);
    hist_kernel<<<(cE1 + 255) / 256, 256, 0, stream>>>(e1_dst, cE1, cnt1);
    chunk_sum_kernel<<<nblk0, 256, 0, stream>>>(cnt0, cN1, bsum0);
    chunk_sum_kernel<<<nblk1, 256, 0, stream>>>(cnt1, cN2, bsum1);
    top_scan_kernel<<<1, 256, 0, stream>>>(bsum0, nblk0, boff0, offs0 + cN1);
    top_scan_kernel<<<1, 256, 0, stream>>>(bsum1, nblk1, boff1, offs1 + cN2);
    chunk_scan_kernel<<<nblk0, 256, 0, stream>>>(cnt0, cN1, boff0, offs0, cursor0);
    chunk_scan_kernel<<<nblk1, 256, 0, stream>>>(cnt1, cN2, boff1, offs1, cursor1);
    scatter_kernel<<<(cE0 + 255) / 256, 256, 0, stream>>>(e0_src, e0_dst, cE0, cursor0, srcidx0);
    scatter_kernel<<<(cE1 + 255) / 256, 256, 0, stream>>>(e1_src, e1_dst, cE1, cursor1, srcidx1);

    bf16_transpose_kernel<<<(256 * 256 + 255) / 256, 256, 0, stream>>>(W1, bt1, 256, 256);
    bf16_transpose_kernel<<<(256 * 64 + 255) / 256, 256, 0, stream>>>(W2, bt2, 256, 64);

    // ----- layer 0 -----
    gemm_bf16_fused<128, 128, 2, 2, false><<<dim3((cN0 + 127) / 128, 2), 256, 0, stream>>>(
        x, bt1, fb, al1, ar1, el0, er0, cN0, 256, 4, cN1);
    agg0_kernel<<<(cN1 + 3) / 4, 256, 0, stream>>>(offs0, srcidx0, el0, er0, fb, b1, h1b);

    // ----- layer 1 -----
    gemm_bf16_fused<128, 64, 4, 1, true><<<dim3((cN1 + 127) / 128, 1), 256, 0, stream>>>(
        h1b, bt2, f2b, al2, ar2, el2, er2, cN1, 256, 1, cN2);
    agg1_kernel<<<(cN2 + 3) / 4, 256, 0, stream>>>(offs1, srcidx1, el2, er2, f2b, b2, out);
}

// Round 4
// 186.441 us; speedup vs baseline: 3.2123x; 1.3149x over previous
//
#include <hip/hip_runtime.h>
#include <cstddef>
#include <cstdint>

constexpr int cN0 = 100000, cN1 = 50000, cN2 = 25000;
constexpr int cE0 = 400000, cE1 = 200000;
constexpr float SLOPE = 0.2f;

typedef short short8  __attribute__((ext_vector_type(8)));
typedef short short4v __attribute__((ext_vector_type(4)));
typedef float f32x4   __attribute__((ext_vector_type(4)));

__device__ __forceinline__ unsigned short f2bf(float x) {
    union { float f; uint32_t u; } c; c.f = x;
    uint32_t u = c.u + 0x7FFFu + ((c.u >> 16) & 1u);   // RNE
    return (unsigned short)(u >> 16);
}
__device__ __forceinline__ float bf2f(uint32_t u) {
    union { uint32_t u; float f; } c; c.u = u << 16; return c.f;
}
__device__ __forceinline__ float lrelu(float x) { return x >= 0.f ? x : SLOPE * x; }

// ---------------- CSR build (merged across both layers) ----------------

__global__ void hist2_kernel(const int* __restrict__ d0, const int* __restrict__ d1,
                             int* __restrict__ cnt0, int* __restrict__ cnt1) {
    int i = blockIdx.x * blockDim.x + threadIdx.x;
    if (i < cE0) atomicAdd(&cnt0[d0[i]], 1);
    int j = i - cE0;
    if (j >= 0 && j < cE1) atomicAdd(&cnt1[d1[j]], 1);
}

__global__ __launch_bounds__(256) void chunk_sum2_kernel(const int* __restrict__ cnt0, int n0,
                                                         const int* __restrict__ cnt1, int n1,
                                                         int* __restrict__ bsum0, int* __restrict__ bsum1,
                                                         int nblk1) {
    const int* cnt = blockIdx.y ? cnt1 : cnt0;
    int n = blockIdx.y ? n1 : n0;
    int* bsum = blockIdx.y ? bsum1 : bsum0;
    if (blockIdx.y && (int)blockIdx.x >= nblk1) return;
    int i = blockIdx.x * 256 + threadIdx.x;
    int v = (i < n) ? cnt[i] : 0;
    #pragma unroll
    for (int o = 32; o; o >>= 1) v += __shfl_xor(v, o);
    __shared__ int ws[4];
    if ((threadIdx.x & 63) == 0) ws[threadIdx.x >> 6] = v;
    __syncthreads();
    if (threadIdx.x == 0) bsum[blockIdx.x] = ws[0] + ws[1] + ws[2] + ws[3];
}

__device__ __forceinline__ int block_exscan(int v, int& total) {
    int lane = threadIdx.x & 63, w = threadIdx.x >> 6;
    int x = v;
    #pragma unroll
    for (int o = 1; o < 64; o <<= 1) { int t = __shfl_up(x, o); if (lane >= o) x += t; }
    __shared__ int ws[4];
    if (lane == 63) ws[w] = x;
    __syncthreads();
    int add = 0;
    #pragma unroll
    for (int i = 0; i < 4; ++i) if (i < w) add += ws[i];
    total = ws[0] + ws[1] + ws[2] + ws[3];
    return add + x - v;
}

// one block does both layers' top-level scans
__global__ __launch_bounds__(256) void top_scan2_kernel(const int* __restrict__ bsum0, int nblk0,
                                                        const int* __restrict__ bsum1, int nblk1,
                                                        int* __restrict__ boff0, int* __restrict__ boff1,
                                                        int* __restrict__ tot0, int* __restrict__ tot1) {
    int i = threadIdx.x;
    int tot;
    int v = (i < nblk0) ? bsum0[i] : 0;
    int e = block_exscan(v, tot);
    if (i < nblk0) boff0[i] = e;
    if (i == 0) *tot0 = tot;
    __syncthreads();
    v = (i < nblk1) ? bsum1[i] : 0;
    e = block_exscan(v, tot);
    if (i < nblk1) boff1[i] = e;
    if (i == 0) *tot1 = tot;
}

__global__ __launch_bounds__(256) void chunk_scan2_kernel(const int* __restrict__ cnt0, int n0,
                                                          const int* __restrict__ cnt1, int n1,
                                                          const int* __restrict__ boff0, const int* __restrict__ boff1,
                                                          int* __restrict__ offs0, int* __restrict__ cursor0,
                                                          int* __restrict__ offs1, int* __restrict__ cursor1,
                                                          int nblk1) {
    const int* cnt = blockIdx.y ? cnt1 : cnt0;
    const int* boff = blockIdx.y ? boff1 : boff0;
    int* offs = blockIdx.y ? offs1 : offs0;
    int* cursor = blockIdx.y ? cursor1 : cursor0;
    int n = blockIdx.y ? n1 : n0;
    if (blockIdx.y && (int)blockIdx.x >= nblk1) return;
    int i = blockIdx.x * 256 + threadIdx.x;
    int v = (i < n) ? cnt[i] : 0;
    int tot; int e = block_exscan(v, tot) + boff[blockIdx.x];
    if (i < n) { offs[i] = e; cursor[i] = e; }
}

__global__ void scatter2_kernel(const int* __restrict__ s0, const int* __restrict__ d0,
                                const int* __restrict__ s1, const int* __restrict__ d1,
                                int* __restrict__ cursor0, int* __restrict__ srcidx0,
                                int* __restrict__ cursor1, int* __restrict__ srcidx1) {
    int i = blockIdx.x * blockDim.x + threadIdx.x;
    if (i < cE0) { int p = atomicAdd(&cursor0[d0[i]], 1); srcidx0[p] = s0[i]; }
    int j = i - cE0;
    if (j >= 0 && j < cE1) { int p = atomicAdd(&cursor1[d1[j]], 1); srcidx1[p] = s1[j]; }
}

// ---------------- weight transpose to bf16 (both weights, one launch) ----------------
__global__ __launch_bounds__(256) void bf16_transpose2_kernel(const float* __restrict__ W1,
                                                              const float* __restrict__ W2,
                                                              short* __restrict__ bt1,
                                                              short* __restrict__ bt2) {
    int i = blockIdx.x * 256 + threadIdx.x;
    if (i < 256 * 256) {
        int k = i >> 8, n = i & 255;
        bt1[(size_t)n * 256 + k] = (short)f2bf(W1[i]);
    } else {
        int j = i - 256 * 256;
        if (j < 256 * 64) {
            int k = j >> 6, n = j & 63;
            bt2[(size_t)n * 256 + k] = (short)f2bf(W2[j]);
        }
    }
}

// ---------------- deep-pipelined bf16 MFMA GEMM, layer 0 ----------------
// 512 threads (8 waves, WR=2 x WC=4), BM=128, BN=256 (full N), BK=32.
// LDS double-buffered, ONE barrier per K-step; loads issued at top, ds_write after compute.
__global__ __launch_bounds__(512, 4) void gemm0_deep(
    const float* __restrict__ A, const short* __restrict__ BT,
    unsigned short* __restrict__ C,
    const float* __restrict__ al, const float* __restrict__ ar,
    float* __restrict__ el, float* __restrict__ er,
    int M, int K, int erN)
{
    constexpr int BM = 128, BN = 256, BK = 32;
    constexpr int PITCH = BK + 8;
    constexpr int WR = 2, WC = 4;
    constexpr int MI = BM / WR / 16;   // 4
    constexpr int NI = BN / WC / 16;   // 4
    constexpr int nh = 4;

    __shared__ short As[2][BM * PITCH];
    __shared__ short Bs[2][BN * PITCH];

    const int tid = threadIdx.x;
    const int w = tid >> 6;
    const int lane = tid & 63;
    const int ln = lane & 15;
    const int kg = lane >> 4;
    const int wr = w / WC;
    const int wc = w % WC;
    const int m0 = blockIdx.x * BM;
    const int N = BN;

    f32x4 acc[MI][NI];
    #pragma unroll
    for (int mi = 0; mi < MI; ++mi)
        #pragma unroll
        for (int ni = 0; ni < NI; ++ni)
            #pragma unroll
            for (int j = 0; j < 4; ++j) acc[mi][ni][j] = 0.f;

    float4 areg[2];    // A: 128x32 f32 / 512 thr = 2 float4
    short8 breg[2];    // B: 256x32 bf16 / 512 thr = 2 short8

    auto loadA = [&](int k0) {
        #pragma unroll
        for (int p = 0; p < 2; ++p) {
            int slot = tid + p * 512;
            int r = slot >> 3;
            int kq = (slot & 7) * 4;
            int gr = m0 + r;
            float4 v = make_float4(0.f, 0.f, 0.f, 0.f);
            if (gr < M) v = *(const float4*)&A[(size_t)gr * K + k0 + kq];
            areg[p] = v;
        }
    };
    auto loadB = [&](int k0) {
        #pragma unroll
        for (int p = 0; p < 2; ++p) {
            int slot = tid + p * 512;
            int r = slot >> 2;
            int kq = (slot & 3) * 8;
            breg[p] = *(const short8*)&BT[(size_t)r * K + k0 + kq];
        }
    };
    auto writeLDS = [&](int c) {
        #pragma unroll
        for (int p = 0; p < 2; ++p) {
            int slot = tid + p * 512;
            int r = slot >> 3;
            int kq = (slot & 7) * 4;
            short4v s;
            s[0] = (short)f2bf(areg[p].x); s[1] = (short)f2bf(areg[p].y);
            s[2] = (short)f2bf(areg[p].z); s[3] = (short)f2bf(areg[p].w);
            *(short4v*)&As[c][r * PITCH + kq] = s;
        }
        #pragma unroll
        for (int p = 0; p < 2; ++p) {
            int slot = tid + p * 512;
            int r = slot >> 2;
            int kq = (slot & 3) * 8;
            *(short8*)&Bs[c][r * PITCH + kq] = breg[p];
        }
    };

    loadA(0); loadB(0);
    writeLDS(0);
    __syncthreads();

    const int T = K / BK;
    int cur = 0;
    for (int t = 0; t < T; ++t) {
        if (t + 1 < T) { loadA((t + 1) * BK); loadB((t + 1) * BK); }  // issue early
        // compute from buf[cur]
        short8 af[MI];
        #pragma unroll
        for (int mi = 0; mi < MI; ++mi)
            af[mi] = *(const short8*)&As[cur][(wr * MI * 16 + mi * 16 + ln) * PITCH + kg * 8];
        #pragma unroll
        for (int ni = 0; ni < NI; ++ni) {
            short8 bf = *(const short8*)&Bs[cur][(wc * NI * 16 + ni * 16 + ln) * PITCH + kg * 8];
            #pragma unroll
            for (int mi = 0; mi < MI; ++mi)
                acc[mi][ni] = __builtin_amdgcn_mfma_f32_16x16x32_bf16(af[mi], bf, acc[mi][ni], 0, 0, 0);
        }
        if (t + 1 < T) { writeLDS(cur ^ 1); cur ^= 1; }               // write late
        __syncthreads();                                               // one barrier/iter
    }

    // epilogue: C store + fused el/er (wave wc owns head h = wc)
    const int h = wc;
    float alv[NI], arv[NI];
    #pragma unroll
    for (int ni = 0; ni < NI; ++ni) {
        alv[ni] = al[h * 64 + ni * 16 + ln];
        arv[ni] = ar[h * 64 + ni * 16 + ln];
    }
    #pragma unroll
    for (int mi = 0; mi < MI; ++mi) {
        float pl[4] = {0, 0, 0, 0}, pr[4] = {0, 0, 0, 0};
        #pragma unroll
        for (int ni = 0; ni < NI; ++ni)
            #pragma unroll
            for (int j = 0; j < 4; ++j) {
                float v = acc[mi][ni][j];
                pl[j] += v * alv[ni];
                pr[j] += v * arv[ni];
            }
        #pragma unroll
        for (int j = 0; j < 4; ++j)
            #pragma unroll
            for (int o = 1; o < 16; o <<= 1) {
                pl[j] += __shfl_xor(pl[j], o);
                pr[j] += __shfl_xor(pr[j], o);
            }
        #pragma unroll
        for (int j = 0; j < 4; ++j) {
            int row = m0 + wr * MI * 16 + mi * 16 + kg * 4 + j;
            if (row < M) {
                #pragma unroll
                for (int ni = 0; ni < NI; ++ni)
                    C[(size_t)row * N + wc * 64 + ni * 16 + ln] = f2bf(acc[mi][ni][j]);
                if (ln == 0) {
                    el[row * nh + h] = pl[j];
                    if (row < erN) er[row * nh + h] = pr[j];
                }
            }
        }
    }
}

// ---------------- layer-1 GEMM (bf16 A), proven template ----------------
template<int BM, int BN, int WR, int WC>
__global__ __launch_bounds__(256) void gemm_bf16_fused(
    const unsigned short* __restrict__ A, const short* __restrict__ BT,
    unsigned short* __restrict__ C,
    const float* __restrict__ al, const float* __restrict__ ar,
    float* __restrict__ el, float* __restrict__ er,
    int M, int K, int nh, int erN)
{
    constexpr int BK = 32;
    constexpr int PITCH = BK + 8;
    constexpr int MI = BM / WR / 16;
    constexpr int NI = BN / WC / 16;
    constexpr int AITB = BM * 4 / 256;
    constexpr int BIT  = BN * 4 / 256;

    __shared__ short As[BM * PITCH];
    __shared__ short Bs[BN * PITCH];

    const int tid = threadIdx.x;
    const int w = tid >> 6;
    const int lane = tid & 63;
    const int ln = lane & 15;
    const int kg = lane >> 4;
    const int wr = w / WC;
    const int wc = w % WC;
    const int m0 = blockIdx.x * BM;
    const int n0 = blockIdx.y * BN;
    const int N = nh * 64;

    f32x4 acc[MI][NI];
    #pragma unroll
    for (int mi = 0; mi < MI; ++mi)
        #pragma unroll
        for (int ni = 0; ni < NI; ++ni)
            #pragma unroll
            for (int j = 0; j < 4; ++j) acc[mi][ni][j] = 0.f;

    short8 aregb[AITB];
    short8 breg[BIT];

    auto loadA = [&](int k0) {
        #pragma unroll
        for (int p = 0; p < AITB; ++p) {
            int slot = tid + p * 256;
            int r = slot >> 2;
            int kq = (slot & 3) * 8;
            int gr = m0 + r;
            short8 v = {};
            if (gr < M) v = *(const short8*)&A[(size_t)gr * K + k0 + kq];
            aregb[p] = v;
        }
    };
    auto loadB = [&](int k0) {
        #pragma unroll
        for (int p = 0; p < BIT; ++p) {
            int slot = tid + p * 256;
            int r = slot >> 2;
            int kq = (slot & 3) * 8;
            breg[p] = *(const short8*)&BT[(size_t)(n0 + r) * K + k0 + kq];
        }
    };
    auto writeLDS = [&]() {
        #pragma unroll
        for (int p = 0; p < AITB; ++p) {
            int slot = tid + p * 256;
            int r = slot >> 2;
            int kq = (slot & 3) * 8;
            *(short8*)&As[r * PITCH + kq] = aregb[p];
        }
        #pragma unroll
        for (int p = 0; p < BIT; ++p) {
            int slot = tid + p * 256;
            int r = slot >> 2;
            int kq = (slot & 3) * 8;
            *(short8*)&Bs[r * PITCH + kq] = breg[p];
        }
    };

    loadA(0); loadB(0);
    const int T = K / BK;
    for (int t = 0; t < T; ++t) {
        writeLDS();
        __syncthreads();
        if (t + 1 < T) { loadA((t + 1) * BK); loadB((t + 1) * BK); }
        short8 af[MI], bf[NI];
        #pragma unroll
        for (int mi = 0; mi < MI; ++mi)
            af[mi] = *(const short8*)&As[(wr * MI * 16 + mi * 16 + ln) * PITCH + kg * 8];
        #pragma unroll
        for (int ni = 0; ni < NI; ++ni)
            bf[ni] = *(const short8*)&Bs[(wc * NI * 16 + ni * 16 + ln) * PITCH + kg * 8];
        #pragma unroll
        for (int mi = 0; mi < MI; ++mi)
            #pragma unroll
            for (int ni = 0; ni < NI; ++ni)
                acc[mi][ni] = __builtin_amdgcn_mfma_f32_16x16x32_bf16(af[mi], bf[ni], acc[mi][ni], 0, 0, 0);
        __syncthreads();
    }

    const int h = (n0 + wc * NI * 16) >> 6;
    float alv[NI], arv[NI];
    #pragma unroll
    for (int ni = 0; ni < NI; ++ni) {
        alv[ni] = al[h * 64 + ni * 16 + ln];
        arv[ni] = ar[h * 64 + ni * 16 + ln];
    }
    #pragma unroll
    for (int mi = 0; mi < MI; ++mi) {
        float pl[4] = {0, 0, 0, 0}, pr[4] = {0, 0, 0, 0};
        #pragma unroll
        for (int ni = 0; ni < NI; ++ni)
            #pragma unroll
            for (int j = 0; j < 4; ++j) {
                float v = acc[mi][ni][j];
                pl[j] += v * alv[ni];
                pr[j] += v * arv[ni];
            }
        #pragma unroll
        for (int j = 0; j < 4; ++j)
            #pragma unroll
            for (int o = 1; o < 16; o <<= 1) {
                pl[j] += __shfl_xor(pl[j], o);
                pr[j] += __shfl_xor(pr[j], o);
            }
        #pragma unroll
        for (int j = 0; j < 4; ++j) {
            int row = m0 + wr * MI * 16 + mi * 16 + kg * 4 + j;
            if (row < M) {
                #pragma unroll
                for (int ni = 0; ni < NI; ++ni)
                    C[(size_t)row * N + n0 + wc * NI * 16 + ni * 16 + ln] = f2bf(acc[mi][ni][j]);
                if (ln == 0) {
                    el[row * nh + h] = pl[j];
                    if (row < erN) er[row * nh + h] = pr[j];
                }
            }
        }
    }
}

// ---------------- aggregation ----------------

// layer0: one wave per dst node.
// Pass A: online max+sum, (16 sub-lanes) x (4 heads).
// Pass B: 2 edges/iter, uint4 (16B=8 bf16)/lane, cross-half combine.
__global__ __launch_bounds__(256) void agg0_kernel(const int* __restrict__ offs,
                                                   const int* __restrict__ srcidx,
                                                   const float* __restrict__ el,
                                                   const float* __restrict__ er,
                                                   const unsigned short* __restrict__ fb,
                                                   const float* __restrict__ bias,
                                                   unsigned short* __restrict__ h1b) {
    int w = threadIdx.x >> 6, lane = threadIdx.x & 63;
    int n = blockIdx.x * 4 + w;
    if (n >= cN1) return;
    int beg = offs[n], end = offs[n + 1];

    int h4 = lane & 3, sub = lane >> 2;
    float erA = er[n * 4 + h4];
    float m = -1e30f, s = 0.f;
    for (int i = beg + sub; i < end; i += 16) {
        int sv = srcidx[i];
        float e = lrelu(el[sv * 4 + h4] + erA);
        if (e > m) { s = s * __expf(m - e) + 1.f; m = e; }
        else s += __expf(e - m);
    }
    #pragma unroll
    for (int o = 4; o < 64; o <<= 1) {
        float m2 = __shfl_xor(m, o), s2 = __shfl_xor(s, o);
        float M = fmaxf(m, m2);
        s = s * __expf(m - M) + s2 * __expf(m2 - M);
        m = M;
    }
    float inv = (s > 0.f) ? 1.f / s : 0.f;

    int half = lane >> 5, lcol = lane & 31;
    int hB = lcol >> 3;
    float mB = __shfl(m, hB);
    float invB = __shfl(inv, hB);
    float erB = __shfl(erA, hB);

    float a[8] = {};
    for (int i = beg + half; i < end; i += 2) {
        int sv = srcidx[i];
        float e = lrelu(el[sv * 4 + hB] + erB);
        float p = __expf(e - mB) * invB;
        uint4 v = *(const uint4*)&fb[(size_t)sv * 256 + lcol * 8];
        a[0] = fmaf(bf2f(v.x & 0xffffu), p, a[0]);
        a[1] = fmaf(bf2f(v.x >> 16),     p, a[1]);
        a[2] = fmaf(bf2f(v.y & 0xffffu), p, a[2]);
        a[3] = fmaf(bf2f(v.y >> 16),     p, a[3]);
        a[4] = fmaf(bf2f(v.z & 0xffffu), p, a[4]);
        a[5] = fmaf(bf2f(v.z >> 16),     p, a[5]);
        a[6] = fmaf(bf2f(v.w & 0xffffu), p, a[6]);
        a[7] = fmaf(bf2f(v.w >> 16),     p, a[7]);
    }
    #pragma unroll
    for (int j = 0; j < 8; ++j) a[j] += __shfl_xor(a[j], 32);
    if (half == 0) {
        short8 r;
        #pragma unroll
        for (int j = 0; j < 8; ++j) {
            float o = a[j] + bias[lcol * 8 + j];
            r[j] = (short)f2bf(o > 0.f ? o : 0.f);
        }
        *(short8*)&h1b[(size_t)n * 256 + lcol * 8] = r;
    }
}

// layer1: one wave per dst node; pass B: 4 edges/iter, uint2 (4 bf16)/lane.
__global__ __launch_bounds__(256) void agg1_kernel(const int* __restrict__ offs,
                                                   const int* __restrict__ srcidx,
                                                   const float* __restrict__ el,
                                                   const float* __restrict__ er,
                                                   const unsigned short* __restrict__ f2b,
                                                   const float* __restrict__ bias,
                                                   float* __restrict__ out) {
    int w = threadIdx.x >> 6, lane = threadIdx.x & 63;
    int n = blockIdx.x * 4 + w;
    if (n >= cN2) return;
    int beg = offs[n], end = offs[n + 1];
    float ern = er[n];

    float m = -1e30f, s = 0.f;
    for (int i = beg + lane; i < end; i += 64) {
        float e = lrelu(el[srcidx[i]] + ern);
        if (e > m) { s = s * __expf(m - e) + 1.f; m = e; }
        else s += __expf(e - m);
    }
    #pragma unroll
    for (int o = 1; o < 64; o <<= 1) {
        float m2 = __shfl_xor(m, o), s2 = __shfl_xor(s, o);
        float M = fmaxf(m, m2);
        s = s * __expf(m - M) + s2 * __expf(m2 - M);
        m = M;
    }
    float inv = (s > 0.f) ? 1.f / s : 0.f;

    int q = lane >> 4, lcol = lane & 15;
    float a[4] = {};
    for (int i = beg + q; i < end; i += 4) {
        int sv = srcidx[i];
        float e = lrelu(el[sv] + ern);
        float p = __expf(e - m) * inv;
        uint2 v = *(const uint2*)&f2b[(size_t)sv * 64 + lcol * 4];
        a[0] = fmaf(bf2f(v.x & 0xffffu), p, a[0]);
        a[1] = fmaf(bf2f(v.x >> 16),     p, a[1]);
        a[2] = fmaf(bf2f(v.y & 0xffffu), p, a[2]);
        a[3] = fmaf(bf2f(v.y >> 16),     p, a[3]);
    }
    #pragma unroll
    for (int o = 16; o < 64; o <<= 1)
        #pragma unroll
        for (int j = 0; j < 4; ++j) a[j] += __shfl_xor(a[j], o);
    if (q == 0) {
        float4 b4 = *(const float4*)&bias[lcol * 4];
        float4 r = make_float4(a[0] + b4.x, a[1] + b4.y, a[2] + b4.z, a[3] + b4.w);
        *(float4*)&out[(size_t)n * 64 + lcol * 4] = r;
    }
}

// ---------------- launch ----------------

extern "C" void kernel_launch(void* const* d_in, const int* in_sizes, int n_in,
                              void* d_out, int out_size, void* d_ws, size_t ws_size,
                              hipStream_t stream) {
    const float* x      = (const float*)d_in[0];
    const int*   e0_src = (const int*)d_in[1];
    const int*   e0_dst = (const int*)d_in[2];
    const int*   e1_src = (const int*)d_in[3];
    const int*   e1_dst = (const int*)d_in[4];
    const float* W1     = (const float*)d_in[5];
    const float* al1    = (const float*)d_in[6];
    const float* ar1    = (const float*)d_in[7];
    const float* b1     = (const float*)d_in[8];
    const float* W2     = (const float*)d_in[9];
    const float* al2    = (const float*)d_in[10];
    const float* ar2    = (const float*)d_in[11];
    const float* b2     = (const float*)d_in[12];
    float* out = (float*)d_out;

    char* ws = (char*)d_ws;
    size_t off = 0;
    auto alloc = [&](size_t bytes) -> void* {
        void* p = ws + off;
        off = (off + bytes + 255) & ~(size_t)255;
        return p;
    };
    unsigned short* fb  = (unsigned short*)alloc((size_t)cN0 * 256 * 2);
    unsigned short* h1b = (unsigned short*)alloc((size_t)cN1 * 256 * 2);
    unsigned short* f2b = (unsigned short*)alloc((size_t)cN1 * 64 * 2);
    float* el0  = (float*)alloc((size_t)cN0 * 4 * 4);
    float* er0  = (float*)alloc((size_t)cN1 * 4 * 4);
    float* el2  = (float*)alloc((size_t)cN1 * 4);
    float* er2  = (float*)alloc((size_t)cN2 * 4);
    short* bt1  = (short*)alloc((size_t)256 * 256 * 2);
    short* bt2  = (short*)alloc((size_t)64 * 256 * 2);
    int* cntB    = (int*)alloc((size_t)(cN1 + cN2) * 4);   // cnt0 | cnt1 contiguous
    int* cnt0    = cntB;
    int* cnt1    = cntB + cN1;
    int* offs0   = (int*)alloc((size_t)(cN1 + 1) * 4);
    int* cursor0 = (int*)alloc((size_t)cN1 * 4);
    int* srcidx0 = (int*)alloc((size_t)cE0 * 4);
    int* offs1   = (int*)alloc((size_t)(cN2 + 1) * 4);
    int* cursor1 = (int*)alloc((size_t)cN2 * 4);
    int* srcidx1 = (int*)alloc((size_t)cE1 * 4);
    int* bsum0   = (int*)alloc(256 * 4);
    int* boff0   = (int*)alloc(256 * 4);
    int* bsum1   = (int*)alloc(256 * 4);
    int* boff1   = (int*)alloc(256 * 4);
    (void)ws_size; (void)n_in; (void)in_sizes; (void)out_size;

    const int nblk0 = (cN1 + 255) / 256;   // 196
    const int nblk1 = (cN2 + 255) / 256;   // 98

    hipMemsetAsync(cntB, 0, (size_t)(cN1 + cN2) * 4, stream);
    hist2_kernel<<<(cE0 + cE1 + 255) / 256, 256, 0, stream>>>(e0_dst, e1_dst, cnt0, cnt1);
    chunk_sum2_kernel<<<dim3(nblk0, 2), 256, 0, stream>>>(cnt0, cN1, cnt1, cN2, bsum0, bsum1, nblk1);
    top_scan2_kernel<<<1, 256, 0, stream>>>(bsum0, nblk0, bsum1, nblk1, boff0, boff1,
                                            offs0 + cN1, offs1 + cN2);
    chunk_scan2_kernel<<<dim3(nblk0, 2), 256, 0, stream>>>(cnt0, cN1, cnt1, cN2, boff0, boff1,
                                                           offs0, cursor0, offs1, cursor1, nblk1);
    scatter2_kernel<<<(cE0 + cE1 + 255) / 256, 256, 0, stream>>>(e0_src, e0_dst, e1_src, e1_dst,
                                                                 cursor0, srcidx0, cursor1, srcidx1);
    bf16_transpose2_kernel<<<(256 * 256 + 256 * 64 + 255) / 256, 256, 0, stream>>>(W1, W2, bt1, bt2);

    // ----- layer 0 -----
    gemm0_deep<<<(cN0 + 127) / 128, 512, 0, stream>>>(x, bt1, fb, al1, ar1, el0, er0, cN0, 256, cN1);
    agg0_kernel<<<(cN1 + 3) / 4, 256, 0, stream>>>(offs0, srcidx0, el0, er0, fb, b1, h1b);

    // ----- layer 1 -----
    gemm_bf16_fused<128, 64, 4, 1><<<dim3((cN1 + 127) / 128, 1), 256, 0, stream>>>(
        h1b, bt2, f2b, al2, ar2, el2, er2, cN1, 256, 1, cN2);
    agg1_kernel<<<(cN2 + 3) / 4, 256, 0, stream>>>(offs1, srcidx1, el2, er2, f2b, b2, out);
}

// Round 5
// 184.339 us; speedup vs baseline: 3.2489x; 1.0114x over previous
//
#include <hip/hip_runtime.h>
#include <cstddef>
#include <cstdint>

constexpr int cN0 = 100000, cN1 = 50000, cN2 = 25000;
constexpr int cE0 = 400000, cE1 = 200000;
constexpr float SLOPE = 0.2f;

typedef short short8  __attribute__((ext_vector_type(8)));
typedef short short4v __attribute__((ext_vector_type(4)));
typedef float f32x4   __attribute__((ext_vector_type(4)));

__device__ __forceinline__ unsigned short f2bf(float x) {
    union { float f; uint32_t u; } c; c.f = x;
    uint32_t u = c.u + 0x7FFFu + ((c.u >> 16) & 1u);   // RNE
    return (unsigned short)(u >> 16);
}
__device__ __forceinline__ float bf2f(uint32_t u) {
    union { uint32_t u; float f; } c; c.u = u << 16; return c.f;
}
__device__ __forceinline__ float lrelu(float x) { return x >= 0.f ? x : SLOPE * x; }

// packed f32->bf16 (RNE, hardware)
__device__ __forceinline__ uint32_t cvtpk(float lo, float hi) {
    uint32_t r;
    asm("v_cvt_pk_bf16_f32 %0, %1, %2" : "=v"(r) : "v"(lo), "v"(hi));
    return r;
}

// async global->LDS, 16B per lane; lds dst must be wave-uniform base (HW adds lane*16)
__device__ __forceinline__ void gload_lds16(const void* g, void* l) {
    __builtin_amdgcn_global_load_lds(
        (const __attribute__((address_space(1))) unsigned int*)g,
        (__attribute__((address_space(3))) unsigned int*)l, 16, 0, 0);
}

// ---------------- CSR build (merged across both layers) ----------------

__global__ void hist2_kernel(const int* __restrict__ d0, const int* __restrict__ d1,
                             int* __restrict__ cnt0, int* __restrict__ cnt1) {
    int i = blockIdx.x * blockDim.x + threadIdx.x;
    if (i < cE0) atomicAdd(&cnt0[d0[i]], 1);
    int j = i - cE0;
    if (j >= 0 && j < cE1) atomicAdd(&cnt1[d1[j]], 1);
}

__global__ __launch_bounds__(256) void chunk_sum2_kernel(const int* __restrict__ cnt0, int n0,
                                                         const int* __restrict__ cnt1, int n1,
                                                         int* __restrict__ bsum0, int* __restrict__ bsum1,
                                                         int nblk1) {
    const int* cnt = blockIdx.y ? cnt1 : cnt0;
    int n = blockIdx.y ? n1 : n0;
    int* bsum = blockIdx.y ? bsum1 : bsum0;
    if (blockIdx.y && (int)blockIdx.x >= nblk1) return;
    int i = blockIdx.x * 256 + threadIdx.x;
    int v = (i < n) ? cnt[i] : 0;
    #pragma unroll
    for (int o = 32; o; o >>= 1) v += __shfl_xor(v, o);
    __shared__ int ws[4];
    if ((threadIdx.x & 63) == 0) ws[threadIdx.x >> 6] = v;
    __syncthreads();
    if (threadIdx.x == 0) bsum[blockIdx.x] = ws[0] + ws[1] + ws[2] + ws[3];
}

__device__ __forceinline__ int block_exscan(int v, int& total) {
    int lane = threadIdx.x & 63, w = threadIdx.x >> 6;
    int x = v;
    #pragma unroll
    for (int o = 1; o < 64; o <<= 1) { int t = __shfl_up(x, o); if (lane >= o) x += t; }
    __shared__ int ws[4];
    if (lane == 63) ws[w] = x;
    __syncthreads();
    int add = 0;
    #pragma unroll
    for (int i = 0; i < 4; ++i) if (i < w) add += ws[i];
    total = ws[0] + ws[1] + ws[2] + ws[3];
    return add + x - v;
}

__global__ __launch_bounds__(256) void top_scan2_kernel(const int* __restrict__ bsum0, int nblk0,
                                                        const int* __restrict__ bsum1, int nblk1,
                                                        int* __restrict__ boff0, int* __restrict__ boff1,
                                                        int* __restrict__ tot0, int* __restrict__ tot1) {
    int i = threadIdx.x;
    int tot;
    int v = (i < nblk0) ? bsum0[i] : 0;
    int e = block_exscan(v, tot);
    if (i < nblk0) boff0[i] = e;
    if (i == 0) *tot0 = tot;
    __syncthreads();
    v = (i < nblk1) ? bsum1[i] : 0;
    e = block_exscan(v, tot);
    if (i < nblk1) boff1[i] = e;
    if (i == 0) *tot1 = tot;
}

__global__ __launch_bounds__(256) void chunk_scan2_kernel(const int* __restrict__ cnt0, int n0,
                                                          const int* __restrict__ cnt1, int n1,
                                                          const int* __restrict__ boff0, const int* __restrict__ boff1,
                                                          int* __restrict__ offs0, int* __restrict__ cursor0,
                                                          int* __restrict__ offs1, int* __restrict__ cursor1,
                                                          int nblk1) {
    const int* cnt = blockIdx.y ? cnt1 : cnt0;
    const int* boff = blockIdx.y ? boff1 : boff0;
    int* offs = blockIdx.y ? offs1 : offs0;
    int* cursor = blockIdx.y ? cursor1 : cursor0;
    int n = blockIdx.y ? n1 : n0;
    if (blockIdx.y && (int)blockIdx.x >= nblk1) return;
    int i = blockIdx.x * 256 + threadIdx.x;
    int v = (i < n) ? cnt[i] : 0;
    int tot; int e = block_exscan(v, tot) + boff[blockIdx.x];
    if (i < n) { offs[i] = e; cursor[i] = e; }
}

__global__ void scatter2_kernel(const int* __restrict__ s0, const int* __restrict__ d0,
                                const int* __restrict__ s1, const int* __restrict__ d1,
                                int* __restrict__ cursor0, int* __restrict__ srcidx0,
                                int* __restrict__ cursor1, int* __restrict__ srcidx1) {
    int i = blockIdx.x * blockDim.x + threadIdx.x;
    if (i < cE0) { int p = atomicAdd(&cursor0[d0[i]], 1); srcidx0[p] = s0[i]; }
    int j = i - cE0;
    if (j >= 0 && j < cE1) { int p = atomicAdd(&cursor1[d1[j]], 1); srcidx1[p] = s1[j]; }
}

// ---------------- weight transpose to bf16 (both weights, one launch) ----------------
__global__ __launch_bounds__(256) void bf16_transpose2_kernel(const float* __restrict__ W1,
                                                              const float* __restrict__ W2,
                                                              short* __restrict__ bt1,
                                                              short* __restrict__ bt2) {
    int i = blockIdx.x * 256 + threadIdx.x;
    if (i < 256 * 256) {
        int k = i >> 8, n = i & 255;
        bt1[(size_t)n * 256 + k] = (short)f2bf(W1[i]);
    } else {
        int j = i - 256 * 256;
        if (j < 256 * 64) {
            int k = j >> 6, n = j & 63;
            bt2[(size_t)n * 256 + k] = (short)f2bf(W2[j]);
        }
    }
}

// ---------------- layer-0 GEMM: async-DMA staged, swizzled LDS ----------------
// 512 threads (8 waves, WR=2 x WC=4), BM=128, BN=256 (full N), BK=32, K=256 fixed.
// A (f32) and B (bf16) staged via global_load_lds with pre-swizzled per-lane SOURCE
// addresses (linear LDS dest); fragment reads apply the matching XOR swizzle.
// A converted f32->bf16 at fragment-read time via v_cvt_pk_bf16_f32.
__global__ __launch_bounds__(512, 4) void gemm0_deep(
    const float* __restrict__ A, const short* __restrict__ BT,
    unsigned short* __restrict__ C,
    const float* __restrict__ al, const float* __restrict__ ar,
    float* __restrict__ el, float* __restrict__ er,
    int M, int erN)
{
    constexpr int T = 8;                 // K=256 / BK=32
    constexpr int nh = 4;
    __shared__ float Asm[2][128 * 32];   // f32 tile, 128B rows, 8x16B chunks/row
    __shared__ short Bsm[2][256 * 32];   // bf16 tile, 64B rows, 4x16B chunks/row

    const int tid = threadIdx.x;
    const int w = tid >> 6;
    const int lane = tid & 63;
    const int ln = lane & 15;
    const int kg = lane >> 4;
    const int wr = w >> 2;               // 0..1
    const int wc = w & 3;                // 0..3
    const int m0 = blockIdx.x * 128;

    f32x4 acc[4][4];
    #pragma unroll
    for (int mi = 0; mi < 4; ++mi)
        #pragma unroll
        for (int ni = 0; ni < 4; ++ni)
            #pragma unroll
            for (int j = 0; j < 4; ++j) acc[mi][ni][j] = 0.f;

    // staging: per wave 2 A-chunks + 2 B-chunks of 1KB each
    auto stageA = [&](int k0, int b) {
        #pragma unroll
        for (int q = 0; q < 2; ++q) {
            int ci = w + q * 8;                       // 0..15
            int r = ci * 8 + (lane >> 3);             // 0..127
            int cl = (lane & 7) ^ (r & 7);            // logical chunk for this phys slot
            int gr = m0 + r; if (gr >= M) gr = M - 1; // clamp (dead rows discarded)
            gload_lds16(&A[(size_t)gr * 256 + k0 + cl * 4], &Asm[b][ci * 256]);
        }
    };
    auto stageB = [&](int k0, int b) {
        #pragma unroll
        for (int q = 0; q < 2; ++q) {
            int ci = w + q * 8;                       // 0..15
            int r = ci * 16 + (lane >> 2);            // 0..255
            int cl = (lane & 3) ^ ((r >> 1) & 3);
            gload_lds16(&BT[(size_t)r * 256 + k0 + cl * 8], &Bsm[b][ci * 512]);
        }
    };

    stageA(0, 0); stageB(0, 0);
    __syncthreads();

    const int swa = ln & 7;
    const int p0base = 2 * kg;           // logical A chunk pair (2kg, 2kg+1)
    const int pb = kg ^ ((ln >> 1) & 3); // B phys chunk

    int cur = 0;
    #pragma unroll
    for (int t = 0; t < T; ++t) {
        if (t + 1 < T) { stageA((t + 1) * 32, cur ^ 1); stageB((t + 1) * 32, cur ^ 1); }

        short8 af[4];
        {
            int pA = p0base ^ swa;
            #pragma unroll
            for (int mi = 0; mi < 4; ++mi) {
                int r = wr * 64 + mi * 16 + ln;
                const f32x4 q0 = *(const f32x4*)&Asm[cur][r * 32 + pA * 4];
                const f32x4 q1 = *(const f32x4*)&Asm[cur][r * 32 + (pA ^ 1) * 4];
                union { uint32_t u[4]; short8 s; } cv;
                cv.u[0] = cvtpk(q0[0], q0[1]);
                cv.u[1] = cvtpk(q0[2], q0[3]);
                cv.u[2] = cvtpk(q1[0], q1[1]);
                cv.u[3] = cvtpk(q1[2], q1[3]);
                af[mi] = cv.s;
            }
        }
        #pragma unroll
        for (int ni = 0; ni < 4; ++ni) {
            int rB = wc * 64 + ni * 16 + ln;
            short8 bf = *(const short8*)&Bsm[cur][rB * 32 + pb * 8];
            #pragma unroll
            for (int mi = 0; mi < 4; ++mi)
                acc[mi][ni] = __builtin_amdgcn_mfma_f32_16x16x32_bf16(af[mi], bf, acc[mi][ni], 0, 0, 0);
        }
        __syncthreads();
        cur ^= 1;
    }

    // epilogue: C store (bf16) + fused el/er (wave wc owns head h = wc)
    const int h = wc;
    float alv[4], arv[4];
    #pragma unroll
    for (int ni = 0; ni < 4; ++ni) {
        alv[ni] = al[h * 64 + ni * 16 + ln];
        arv[ni] = ar[h * 64 + ni * 16 + ln];
    }
    #pragma unroll
    for (int mi = 0; mi < 4; ++mi) {
        float pl[4] = {0, 0, 0, 0}, pr[4] = {0, 0, 0, 0};
        #pragma unroll
        for (int ni = 0; ni < 4; ++ni)
            #pragma unroll
            for (int j = 0; j < 4; ++j) {
                float v = acc[mi][ni][j];
                pl[j] += v * alv[ni];
                pr[j] += v * arv[ni];
            }
        #pragma unroll
        for (int j = 0; j < 4; ++j)
            #pragma unroll
            for (int o = 1; o < 16; o <<= 1) {
                pl[j] += __shfl_xor(pl[j], o);
                pr[j] += __shfl_xor(pr[j], o);
            }
        #pragma unroll
        for (int j = 0; j < 4; ++j) {
            int row = m0 + wr * 64 + mi * 16 + kg * 4 + j;
            if (row < M) {
                #pragma unroll
                for (int ni = 0; ni < 4; ++ni)
                    C[(size_t)row * 256 + wc * 64 + ni * 16 + ln] = f2bf(acc[mi][ni][j]);
                if (ln == 0) {
                    el[row * nh + h] = pl[j];
                    if (row < erN) er[row * nh + h] = pr[j];
                }
            }
        }
    }
}

// ---------------- layer-1 GEMM (bf16 A), proven template ----------------
template<int BM, int BN, int WR, int WC>
__global__ __launch_bounds__(256) void gemm_bf16_fused(
    const unsigned short* __restrict__ A, const short* __restrict__ BT,
    unsigned short* __restrict__ C,
    const float* __restrict__ al, const float* __restrict__ ar,
    float* __restrict__ el, float* __restrict__ er,
    int M, int K, int nh, int erN)
{
    constexpr int BK = 32;
    constexpr int PITCH = BK + 8;
    constexpr int MI = BM / WR / 16;
    constexpr int NI = BN / WC / 16;
    constexpr int AITB = BM * 4 / 256;
    constexpr int BIT  = BN * 4 / 256;

    __shared__ short As[BM * PITCH];
    __shared__ short Bs[BN * PITCH];

    const int tid = threadIdx.x;
    const int w = tid >> 6;
    const int lane = tid & 63;
    const int ln = lane & 15;
    const int kg = lane >> 4;
    const int wr = w / WC;
    const int wc = w % WC;
    const int m0 = blockIdx.x * BM;
    const int n0 = blockIdx.y * BN;
    const int N = nh * 64;

    f32x4 acc[MI][NI];
    #pragma unroll
    for (int mi = 0; mi < MI; ++mi)
        #pragma unroll
        for (int ni = 0; ni < NI; ++ni)
            #pragma unroll
            for (int j = 0; j < 4; ++j) acc[mi][ni][j] = 0.f;

    short8 aregb[AITB];
    short8 breg[BIT];

    auto loadA = [&](int k0) {
        #pragma unroll
        for (int p = 0; p < AITB; ++p) {
            int slot = tid + p * 256;
            int r = slot >> 2;
            int kq = (slot & 3) * 8;
            int gr = m0 + r;
            short8 v = {};
            if (gr < M) v = *(const short8*)&A[(size_t)gr * K + k0 + kq];
            aregb[p] = v;
        }
    };
    auto loadB = [&](int k0) {
        #pragma unroll
        for (int p = 0; p < BIT; ++p) {
            int slot = tid + p * 256;
            int r = slot >> 2;
            int kq = (slot & 3) * 8;
            breg[p] = *(const short8*)&BT[(size_t)(n0 + r) * K + k0 + kq];
        }
    };
    auto writeLDS = [&]() {
        #pragma unroll
        for (int p = 0; p < AITB; ++p) {
            int slot = tid + p * 256;
            int r = slot >> 2;
            int kq = (slot & 3) * 8;
            *(short8*)&As[r * PITCH + kq] = aregb[p];
        }
        #pragma unroll
        for (int p = 0; p < BIT; ++p) {
            int slot = tid + p * 256;
            int r = slot >> 2;
            int kq = (slot & 3) * 8;
            *(short8*)&Bs[r * PITCH + kq] = breg[p];
        }
    };

    loadA(0); loadB(0);
    const int T = K / BK;
    for (int t = 0; t < T; ++t) {
        writeLDS();
        __syncthreads();
        if (t + 1 < T) { loadA((t + 1) * BK); loadB((t + 1) * BK); }
        short8 af[MI], bf[NI];
        #pragma unroll
        for (int mi = 0; mi < MI; ++mi)
            af[mi] = *(const short8*)&As[(wr * MI * 16 + mi * 16 + ln) * PITCH + kg * 8];
        #pragma unroll
        for (int ni = 0; ni < NI; ++ni)
            bf[ni] = *(const short8*)&Bs[(wc * NI * 16 + ni * 16 + ln) * PITCH + kg * 8];
        #pragma unroll
        for (int mi = 0; mi < MI; ++mi)
            #pragma unroll
            for (int ni = 0; ni < NI; ++ni)
                acc[mi][ni] = __builtin_amdgcn_mfma_f32_16x16x32_bf16(af[mi], bf[ni], acc[mi][ni], 0, 0, 0);
        __syncthreads();
    }

    const int h = (n0 + wc * NI * 16) >> 6;
    float alv[NI], arv[NI];
    #pragma unroll
    for (int ni = 0; ni < NI; ++ni) {
        alv[ni] = al[h * 64 + ni * 16 + ln];
        arv[ni] = ar[h * 64 + ni * 16 + ln];
    }
    #pragma unroll
    for (int mi = 0; mi < MI; ++mi) {
        float pl[4] = {0, 0, 0, 0}, pr[4] = {0, 0, 0, 0};
        #pragma unroll
        for (int ni = 0; ni < NI; ++ni)
            #pragma unroll
            for (int j = 0; j < 4; ++j) {
                float v = acc[mi][ni][j];
                pl[j] += v * alv[ni];
                pr[j] += v * arv[ni];
            }
        #pragma unroll
        for (int j = 0; j < 4; ++j)
            #pragma unroll
            for (int o = 1; o < 16; o <<= 1) {
                pl[j] += __shfl_xor(pl[j], o);
                pr[j] += __shfl_xor(pr[j], o);
            }
        #pragma unroll
        for (int j = 0; j < 4; ++j) {
            int row = m0 + wr * MI * 16 + mi * 16 + kg * 4 + j;
            if (row < M) {
                #pragma unroll
                for (int ni = 0; ni < NI; ++ni)
                    C[(size_t)row * N + n0 + wc * NI * 16 + ni * 16 + ln] = f2bf(acc[mi][ni][j]);
                if (ln == 0) {
                    el[row * nh + h] = pl[j];
                    if (row < erN) er[row * nh + h] = pr[j];
                }
            }
        }
    }
}

// ---------------- aggregation ----------------

// layer0: one wave per dst node.
// Pass A: online max+sum, (16 sub-lanes) x (4 heads).
// Pass B: 2 edges/iter, uint4 (16B=8 bf16)/lane, cross-half combine.
__global__ __launch_bounds__(256) void agg0_kernel(const int* __restrict__ offs,
                                                   const int* __restrict__ srcidx,
                                                   const float* __restrict__ el,
                                                   const float* __restrict__ er,
                                                   const unsigned short* __restrict__ fb,
                                                   const float* __restrict__ bias,
                                                   unsigned short* __restrict__ h1b) {
    int w = threadIdx.x >> 6, lane = threadIdx.x & 63;
    int n = blockIdx.x * 4 + w;
    if (n >= cN1) return;
    int beg = offs[n], end = offs[n + 1];

    int h4 = lane & 3, sub = lane >> 2;
    float erA = er[n * 4 + h4];
    float m = -1e30f, s = 0.f;
    for (int i = beg + sub; i < end; i += 16) {
        int sv = srcidx[i];
        float e = lrelu(el[sv * 4 + h4] + erA);
        if (e > m) { s = s * __expf(m - e) + 1.f; m = e; }
        else s += __expf(e - m);
    }
    #pragma unroll
    for (int o = 4; o < 64; o <<= 1) {
        float m2 = __shfl_xor(m, o), s2 = __shfl_xor(s, o);
        float M = fmaxf(m, m2);
        s = s * __expf(m - M) + s2 * __expf(m2 - M);
        m = M;
    }
    float inv = (s > 0.f) ? 1.f / s : 0.f;

    int half = lane >> 5, lcol = lane & 31;
    int hB = lcol >> 3;
    float mB = __shfl(m, hB);
    float invB = __shfl(inv, hB);
    float erB = __shfl(erA, hB);

    float a[8] = {};
    for (int i = beg + half; i < end; i += 2) {
        int sv = srcidx[i];
        float e = lrelu(el[sv * 4 + hB] + erB);
        float p = __expf(e - mB) * invB;
        uint4 v = *(const uint4*)&fb[(size_t)sv * 256 + lcol * 8];
        a[0] = fmaf(bf2f(v.x & 0xffffu), p, a[0]);
        a[1] = fmaf(bf2f(v.x >> 16),     p, a[1]);
        a[2] = fmaf(bf2f(v.y & 0xffffu), p, a[2]);
        a[3] = fmaf(bf2f(v.y >> 16),     p, a[3]);
        a[4] = fmaf(bf2f(v.z & 0xffffu), p, a[4]);
        a[5] = fmaf(bf2f(v.z >> 16),     p, a[5]);
        a[6] = fmaf(bf2f(v.w & 0xffffu), p, a[6]);
        a[7] = fmaf(bf2f(v.w >> 16),     p, a[7]);
    }
    #pragma unroll
    for (int j = 0; j < 8; ++j) a[j] += __shfl_xor(a[j], 32);
    if (half == 0) {
        short8 r;
        #pragma unroll
        for (int j = 0; j < 8; ++j) {
            float o = a[j] + bias[lcol * 8 + j];
            r[j] = (short)f2bf(o > 0.f ? o : 0.f);
        }
        *(short8*)&h1b[(size_t)n * 256 + lcol * 8] = r;
    }
}

// layer1: one wave per dst node; pass B: 4 edges/iter, uint2 (4 bf16)/lane.
__global__ __launch_bounds__(256) void agg1_kernel(const int* __restrict__ offs,
                                                   const int* __restrict__ srcidx,
                                                   const float* __restrict__ el,
                                                   const float* __restrict__ er,
                                                   const unsigned short* __restrict__ f2b,
                                                   const float* __restrict__ bias,
                                                   float* __restrict__ out) {
    int w = threadIdx.x >> 6, lane = threadIdx.x & 63;
    int n = blockIdx.x * 4 + w;
    if (n >= cN2) return;
    int beg = offs[n], end = offs[n + 1];
    float ern = er[n];

    float m = -1e30f, s = 0.f;
    for (int i = beg + lane; i < end; i += 64) {
        float e = lrelu(el[srcidx[i]] + ern);
        if (e > m) { s = s * __expf(m - e) + 1.f; m = e; }
        else s += __expf(e - m);
    }
    #pragma unroll
    for (int o = 1; o < 64; o <<= 1) {
        float m2 = __shfl_xor(m, o), s2 = __shfl_xor(s, o);
        float M = fmaxf(m, m2);
        s = s * __expf(m - M) + s2 * __expf(m2 - M);
        m = M;
    }
    float inv = (s > 0.f) ? 1.f / s : 0.f;

    int q = lane >> 4, lcol = lane & 15;
    float a[4] = {};
    for (int i = beg + q; i < end; i += 4) {
        int sv = srcidx[i];
        float e = lrelu(el[sv] + ern);
        float p = __expf(e - m) * inv;
        uint2 v = *(const uint2*)&f2b[(size_t)sv * 64 + lcol * 4];
        a[0] = fmaf(bf2f(v.x & 0xffffu), p, a[0]);
        a[1] = fmaf(bf2f(v.x >> 16),     p, a[1]);
        a[2] = fmaf(bf2f(v.y & 0xffffu), p, a[2]);
        a[3] = fmaf(bf2f(v.y >> 16),     p, a[3]);
    }
    #pragma unroll
    for (int o = 16; o < 64; o <<= 1)
        #pragma unroll
        for (int j = 0; j < 4; ++j) a[j] += __shfl_xor(a[j], o);
    if (q == 0) {
        float4 b4 = *(const float4*)&bias[lcol * 4];
        float4 r = make_float4(a[0] + b4.x, a[1] + b4.y, a[2] + b4.z, a[3] + b4.w);
        *(float4*)&out[(size_t)n * 64 + lcol * 4] = r;
    }
}

// ---------------- launch ----------------

extern "C" void kernel_launch(void* const* d_in, const int* in_sizes, int n_in,
                              void* d_out, int out_size, void* d_ws, size_t ws_size,
                              hipStream_t stream) {
    const float* x      = (const float*)d_in[0];
    const int*   e0_src = (const int*)d_in[1];
    const int*   e0_dst = (const int*)d_in[2];
    const int*   e1_src = (const int*)d_in[3];
    const int*   e1_dst = (const int*)d_in[4];
    const float* W1     = (const float*)d_in[5];
    const float* al1    = (const float*)d_in[6];
    const float* ar1    = (const float*)d_in[7];
    const float* b1     = (const float*)d_in[8];
    const float* W2     = (const float*)d_in[9];
    const float* al2    = (const float*)d_in[10];
    const float* ar2    = (const float*)d_in[11];
    const float* b2     = (const float*)d_in[12];
    float* out = (float*)d_out;

    char* ws = (char*)d_ws;
    size_t off = 0;
    auto alloc = [&](size_t bytes) -> void* {
        void* p = ws + off;
        off = (off + bytes + 255) & ~(size_t)255;
        return p;
    };
    unsigned short* fb  = (unsigned short*)alloc((size_t)cN0 * 256 * 2);
    unsigned short* h1b = (unsigned short*)alloc((size_t)cN1 * 256 * 2);
    unsigned short* f2b = (unsigned short*)alloc((size_t)cN1 * 64 * 2);
    float* el0  = (float*)alloc((size_t)cN0 * 4 * 4);
    float* er0  = (float*)alloc((size_t)cN1 * 4 * 4);
    float* el2  = (float*)alloc((size_t)cN1 * 4);
    float* er2  = (float*)alloc((size_t)cN2 * 4);
    short* bt1  = (short*)alloc((size_t)256 * 256 * 2);
    short* bt2  = (short*)alloc((size_t)64 * 256 * 2);
    int* cntB    = (int*)alloc((size_t)(cN1 + cN2) * 4);
    int* cnt0    = cntB;
    int* cnt1    = cntB + cN1;
    int* offs0   = (int*)alloc((size_t)(cN1 + 1) * 4);
    int* cursor0 = (int*)alloc((size_t)cN1 * 4);
    int* srcidx0 = (int*)alloc((size_t)cE0 * 4);
    int* offs1   = (int*)alloc((size_t)(cN2 + 1) * 4);
    int* cursor1 = (int*)alloc((size_t)cN2 * 4);
    int* srcidx1 = (int*)alloc((size_t)cE1 * 4);
    int* bsum0   = (int*)alloc(256 * 4);
    int* boff0   = (int*)alloc(256 * 4);
    int* bsum1   = (int*)alloc(256 * 4);
    int* boff1   = (int*)alloc(256 * 4);
    (void)ws_size; (void)n_in; (void)in_sizes; (void)out_size;

    const int nblk0 = (cN1 + 255) / 256;   // 196
    const int nblk1 = (cN2 + 255) / 256;   // 98

    hipMemsetAsync(cntB, 0, (size_t)(cN1 + cN2) * 4, stream);
    hist2_kernel<<<(cE0 + cE1 + 255) / 256, 256, 0, stream>>>(e0_dst, e1_dst, cnt0, cnt1);
    chunk_sum2_kernel<<<dim3(nblk0, 2), 256, 0, stream>>>(cnt0, cN1, cnt1, cN2, bsum0, bsum1, nblk1);
    top_scan2_kernel<<<1, 256, 0, stream>>>(bsum0, nblk0, bsum1, nblk1, boff0, boff1,
                                            offs0 + cN1, offs1 + cN2);
    chunk_scan2_kernel<<<dim3(nblk0, 2), 256, 0, stream>>>(cnt0, cN1, cnt1, cN2, boff0, boff1,
                                                           offs0, cursor0, offs1, cursor1, nblk1);
    scatter2_kernel<<<(cE0 + cE1 + 255) / 256, 256, 0, stream>>>(e0_src, e0_dst, e1_src, e1_dst,
                                                                 cursor0, srcidx0, cursor1, srcidx1);
    bf16_transpose2_kernel<<<(256 * 256 + 256 * 64 + 255) / 256, 256, 0, stream>>>(W1, W2, bt1, bt2);

    // ----- layer 0 -----
    gemm0_deep<<<(cN0 + 127) / 128, 512, 0, stream>>>(x, bt1, fb, al1, ar1, el0, er0, cN0, cN1);
    agg0_kernel<<<(cN1 + 3) / 4, 256, 0, stream>>>(offs0, srcidx0, el0, er0, fb, b1, h1b);

    // ----- layer 1 -----
    gemm_bf16_fused<128, 64, 4, 1><<<dim3((cN1 + 127) / 128, 1), 256, 0, stream>>>(
        h1b, bt2, f2b, al2, ar2, el2, er2, cN1, 256, 1, cN2);
    agg1_kernel<<<(cN2 + 3) / 4, 256, 0, stream>>>(offs1, srcidx1, el2, er2, f2b, b2, out);
}